// Round 17
// baseline (191.593 us; speedup 1.0000x reference)
//
#include <hip/hip_runtime.h>

#define N_NODES 50000
#define E_EDGES 800000
#define FEAT    128
#define KORD    3
#define BN_EPS  1e-5f
#define NB1     49          // ceil(50000/1024) scan blocks
#define NBUK    49          // coarse buckets (dst >> 10)
#define BCAP    20480       // bucket capacity
#define NSHARD  16          // BN-stats atomic shards
#define NWB_BLKS 12500      // (N_NODES*64)/256

typedef __fp16 f16x2 __attribute__((ext_vector_type(2)));
typedef __fp16 f16x8 __attribute__((ext_vector_type(8)));
typedef __attribute__((ext_vector_type(4))) float f32x4;

__device__ __forceinline__ unsigned h2u(f16x2 h) { union { f16x2 h; unsigned u; } c; c.h = h; return c.u; }
__device__ __forceinline__ f16x2 u2h(unsigned u) { union { unsigned u; f16x2 h; } c; c.u = u; return c.h; }

// async global->LDS, 16B per lane (lane lands at ldsbase + lane*16)
__device__ __forceinline__ void gload16(const void* g, void* l) {
    __builtin_amdgcn_global_load_lds(
        (const __attribute__((address_space(1))) unsigned int*)g,
        (__attribute__((address_space(3))) unsigned int*)l, 16, 0, 0);
}

// ---- per node: feature->f16, pack {coords, g=attW@f}; tail blocks: fold
//      GT[o][k*128+i] = sum_j L[k][i][j]*W[o][j]  (gprep merged) ----
__global__ void g_cast(const float* __restrict__ feat,
                       const float* __restrict__ coords,
                       const float* __restrict__ attW,
                       const float* __restrict__ W,
                       const float* __restrict__ L,
                       __fp16* __restrict__ fh,
                       float4* __restrict__ pk,
                       __fp16* __restrict__ GT) {
    __shared__ float wrow[FEAT];
    if (blockIdx.x >= NWB_BLKS) {            // gprep tail blocks (128)
        const int o = blockIdx.x - NWB_BLKS;
        const int i = threadIdx.x;
        if (i < FEAT) wrow[i] = W[o * FEAT + i];
        __syncthreads();
        if (i < FEAT) {
            #pragma unroll
            for (int k = 0; k < KORD; ++k) {
                const float* lp = L + ((size_t)k * FEAT + i) * FEAT;
                float acc = 0.f;
                #pragma unroll 8
                for (int j = 0; j < FEAT; ++j) acc = fmaf(lp[j], wrow[j], acc);
                GT[(size_t)o * 384 + k * FEAT + i] = (__fp16)acc;
            }
        }
        return;
    }
    const int node = (blockIdx.x * blockDim.x + threadIdx.x) >> 6;
    const int lane = threadIdx.x & 63;
    if (node >= N_NODES) return;
    const float2 f = *(const float2*)(feat + (size_t)node * FEAT + lane * 2);
    *(f16x2*)(fh + (size_t)node * FEAT + lane * 2) = __builtin_amdgcn_cvt_pkrtz(f.x, f.y);
    float gg[3];
    #pragma unroll
    for (int j = 0; j < 3; ++j) {
        float p = f.x * attW[j * FEAT + lane * 2] + f.y * attW[j * FEAT + lane * 2 + 1];
        #pragma unroll
        for (int off = 32; off; off >>= 1) p += __shfl_xor(p, off);
        gg[j] = p;
    }
    if (lane == 0) {
        const float c0 = coords[node * 3 + 0], c1 = coords[node * 3 + 1], c2 = coords[node * 3 + 2];
        pk[2 * node]     = make_float4(c0, c1, c2, gg[0]);
        pk[2 * node + 1] = make_float4(gg[1], gg[2], 0.f, 0.f);
    }
}

// ============ CSR build ============
__global__ __launch_bounds__(256)
void bucketA(const int* __restrict__ src, const int* __restrict__ dst,
             const int* __restrict__ order,
             int* __restrict__ cnt, int* __restrict__ gcur, int2* __restrict__ bbuf) {
    __shared__ int lcnt[NBUK];
    __shared__ int lbase[NBUK];
    const int tid = threadIdx.x;
    if (tid < NBUK) lcnt[tid] = 0;
    __syncthreads();
    const int e0 = blockIdx.x * 2048;
    int b[8], r[8], so[8], dd[8];
    #pragma unroll
    for (int i = 0; i < 8; ++i) {
        const int e = e0 + i * 256 + tid;
        if (e < E_EDGES) {
            dd[i] = dst[e];
            so[i] = (order[e] << 16) | src[e];
            b[i] = dd[i] >> 10;
            r[i] = atomicAdd(&lcnt[b[i]], 1);
            atomicAdd(cnt + dd[i], 1);
        } else b[i] = -1;
    }
    __syncthreads();
    if (tid < NBUK) lbase[tid] = atomicAdd(&gcur[tid], lcnt[tid]);
    __syncthreads();
    #pragma unroll
    for (int i = 0; i < 8; ++i)
        if (b[i] >= 0)
            bbuf[(size_t)b[i] * BCAP + lbase[b[i]] + r[i]] = make_int2(so[i], dd[i]);
}

__global__ __launch_bounds__(256)
void scan1(const int* __restrict__ cnt, int* __restrict__ rowptr, int* __restrict__ bsum) {
    __shared__ int lds[256];
    const int b = blockIdx.x, t = threadIdx.x;
    const int base = b * 1024 + t * 4;
    int v[4];
    #pragma unroll
    for (int i = 0; i < 4; ++i) v[i] = (base + i < N_NODES) ? cnt[base + i] : 0;
    lds[t] = v[0] + v[1] + v[2] + v[3];
    __syncthreads();
    for (int off = 1; off < 256; off <<= 1) {
        const int u = (t >= off) ? lds[t - off] : 0;
        __syncthreads();
        lds[t] += u;
        __syncthreads();
    }
    int excl = t ? lds[t - 1] : 0;
    if (t == 255) bsum[b] = lds[255];
    #pragma unroll
    for (int i = 0; i < 4; ++i) {
        if (base + i < N_NODES) rowptr[base + i] = excl;
        excl += v[i];
    }
}

// ---- scan3 (scan2 folded: wave 0 rescans the 49 block sums) ----
__global__ void scan3(int* __restrict__ rowptr, int* __restrict__ cursor,
                      const int* __restrict__ bsum) {
    __shared__ int boff_s[64];
    const int t = threadIdx.x;
    if (t < 64) {
        const int v = (t < NB1) ? bsum[t] : 0;
        int incl = v;
        #pragma unroll
        for (int off = 1; off < 64; off <<= 1) {
            const int u = __shfl_up(incl, off);
            if (t >= off) incl += u;
        }
        boff_s[t] = incl - v;
    }
    __syncthreads();
    const int i = blockIdx.x * 256 + t;
    if (i < N_NODES) {
        const int v = rowptr[i] + boff_s[i >> 10];
        rowptr[i] = v;
        cursor[i] = v;
    }
    if (i == 0) rowptr[N_NODES] = E_EDGES;
}

// ---- bucketB: scatter to CSR slots + per-edge attention logits/invdist ----
// pk[dst] reads hit a ~32KB window (bucket = dst>>10); pk[src] is the gather.
__global__ void bucketB(const int* __restrict__ gcur, const int2* __restrict__ bbuf,
                        const float4* __restrict__ pk,
                        int* __restrict__ cursor, int* __restrict__ sord_p,
                        float* __restrict__ att_p, float* __restrict__ invd_p) {
    const int b = blockIdx.x >> 3;
    const int seg = blockIdx.x & 7;
    const int n = gcur[b];
    const int lo = (int)((long)n * seg / 8), hi = (int)((long)n * (seg + 1) / 8);
    for (int i = lo + (int)threadIdx.x; i < hi; i += 256) {
        const int2 ent = bbuf[(size_t)b * BCAP + i];
        const int s = ent.x & 0xFFFF;
        const int d = ent.y;
        const float4 a0 = pk[2 * s], a1 = pk[2 * s + 1], c0 = pk[2 * d];
        const float dx = a0.x - c0.x, dy = a0.y - c0.y, dz = a0.z - c0.z;
        const float att  = dx * a0.w + dy * a1.x + dz * a1.y;
        const float invd = 1.f / (dx * dx + dy * dy + dz * dz + 1.f);
        const int pos = atomicAdd(cursor + d, 1);
        sord_p[pos] = ent.x;
        att_p[pos]  = att;
        invd_p[pos] = invd;
    }
}

// ---- segment softmax + per-order gather-aggregate (stream-only + fh gather)
// Phase 2: t-loop step 8 -> 2 independent 256B row-gathers in flight per
// 16-lane group. Stash entries >= ne are zero-weight (dead lanes write 0).
__global__ void segagg(const int* __restrict__ sord_p,
                       const float* __restrict__ att_p,
                       const float* __restrict__ invd_p,
                       const int* __restrict__ rowptr,
                       const __fp16* __restrict__ fh,
                       __fp16* __restrict__ agg) {
    __shared__ uint4 stash[4][64];
    const int node = (blockIdx.x * blockDim.x + threadIdx.x) >> 6;
    const int lane = threadIdx.x & 63;
    const int wid  = threadIdx.x >> 6;
    if (node >= N_NODES) return;
    const int beg = rowptr[node], end = rowptr[node + 1];

    // phase 1: online (m,s) over contiguous att_p; cache chunk-0 value
    float a0c = -1e30f;
    float m = -1e30f, s = 0.f;
    int nch = 0;
    for (int cb = beg; cb < end; cb += 64, ++nch) {
        const int p = cb + lane;
        const float a = (p < end) ? att_p[p] : -1e30f;
        if (nch == 0) a0c = a;
        const float mn = fmaxf(m, a);
        s = s * __expf(m - mn) + ((p < end) ? __expf(a - mn) : 0.f);
        m = mn;
    }
    #pragma unroll
    for (int off = 32; off; off >>= 1) {
        const float mo = __shfl_xor(m, off), so_ = __shfl_xor(s, off);
        const float mn = fmaxf(m, mo);
        s = s * __expf(m - mn) + so_ * __expf(mo - mn);
        m = mn;
    }
    const float inv_s = s > 0.f ? 1.f / s : 0.f;

    // phase 2: 4-edge groups, 2 gathers in flight
    const int grp = lane >> 4;
    const int fl  = lane & 15;
    f16x2 ac[3][4];
    #pragma unroll
    for (int o = 0; o < 3; ++o)
        #pragma unroll
        for (int q = 0; q < 4; ++q) ac[o][q] = (f16x2){0, 0};

    int ch = 0;
    for (int cb = beg; cb < end; cb += 64, ++ch) {
        const int p = cb + lane;
        float wl = 0.f; int so = 0;
        if (p < end) {
            const float a = (ch == 0) ? a0c : att_p[p];
            wl = __expf(a - m) * inv_s * invd_p[p];
            so = sord_p[p];
        }
        const int k = so >> 16;
        const __fp16 wh = (__fp16)wl;
        f16x2 w2; w2.x = wh; w2.y = wh;
        const unsigned uw = h2u(w2);
        stash[wid][lane] = make_uint4(k == 0 ? uw : 0u, k == 1 ? uw : 0u,
                                      k == 2 ? uw : 0u, (unsigned)(so & 0xFFFF));
        const int ne = min(64, end - cb);
        const uint4* st = stash[wid];
        for (int t = 0; t < ne; t += 8) {
            const uint4 e1 = st[t + grp];
            const uint4 e2 = st[t + 4 + grp];
            const uint4 v1 = *(const uint4*)(fh + ((size_t)e1.w << 7) + fl * 8);
            const uint4 v2 = *(const uint4*)(fh + ((size_t)e2.w << 7) + fl * 8);
            {
                const f16x2 w0 = u2h(e1.x), w1 = u2h(e1.y), w2v = u2h(e1.z);
                const f16x2 va = u2h(v1.x), vb = u2h(v1.y), vc = u2h(v1.z), vd = u2h(v1.w);
                ac[0][0] = __builtin_elementwise_fma(va, w0, ac[0][0]);
                ac[0][1] = __builtin_elementwise_fma(vb, w0, ac[0][1]);
                ac[0][2] = __builtin_elementwise_fma(vc, w0, ac[0][2]);
                ac[0][3] = __builtin_elementwise_fma(vd, w0, ac[0][3]);
                ac[1][0] = __builtin_elementwise_fma(va, w1, ac[1][0]);
                ac[1][1] = __builtin_elementwise_fma(vb, w1, ac[1][1]);
                ac[1][2] = __builtin_elementwise_fma(vc, w1, ac[1][2]);
                ac[1][3] = __builtin_elementwise_fma(vd, w1, ac[1][3]);
                ac[2][0] = __builtin_elementwise_fma(va, w2v, ac[2][0]);
                ac[2][1] = __builtin_elementwise_fma(vb, w2v, ac[2][1]);
                ac[2][2] = __builtin_elementwise_fma(vc, w2v, ac[2][2]);
                ac[2][3] = __builtin_elementwise_fma(vd, w2v, ac[2][3]);
            }
            {
                const f16x2 w0 = u2h(e2.x), w1 = u2h(e2.y), w2v = u2h(e2.z);
                const f16x2 va = u2h(v2.x), vb = u2h(v2.y), vc = u2h(v2.z), vd = u2h(v2.w);
                ac[0][0] = __builtin_elementwise_fma(va, w0, ac[0][0]);
                ac[0][1] = __builtin_elementwise_fma(vb, w0, ac[0][1]);
                ac[0][2] = __builtin_elementwise_fma(vc, w0, ac[0][2]);
                ac[0][3] = __builtin_elementwise_fma(vd, w0, ac[0][3]);
                ac[1][0] = __builtin_elementwise_fma(va, w1, ac[1][0]);
                ac[1][1] = __builtin_elementwise_fma(vb, w1, ac[1][1]);
                ac[1][2] = __builtin_elementwise_fma(vc, w1, ac[1][2]);
                ac[1][3] = __builtin_elementwise_fma(vd, w1, ac[1][3]);
                ac[2][0] = __builtin_elementwise_fma(va, w2v, ac[2][0]);
                ac[2][1] = __builtin_elementwise_fma(vb, w2v, ac[2][1]);
                ac[2][2] = __builtin_elementwise_fma(vc, w2v, ac[2][2]);
                ac[2][3] = __builtin_elementwise_fma(vd, w2v, ac[2][3]);
            }
        }
    }
    #pragma unroll
    for (int o = 0; o < 3; ++o)
        #pragma unroll
        for (int q = 0; q < 4; ++q) {
            ac[o][q] = ac[o][q] + u2h(__shfl_xor((int)h2u(ac[o][q]), 16));
            ac[o][q] = ac[o][q] + u2h(__shfl_xor((int)h2u(ac[o][q]), 32));
        }
    if (lane < 16) {
        __fp16* row = agg + (size_t)node * 384 + fl * 8;
        *(uint4*)(row)       = make_uint4(h2u(ac[0][0]), h2u(ac[0][1]), h2u(ac[0][2]), h2u(ac[0][3]));
        *(uint4*)(row + 128) = make_uint4(h2u(ac[1][0]), h2u(ac[1][1]), h2u(ac[1][2]), h2u(ac[1][3]));
        *(uint4*)(row + 256) = make_uint4(h2u(ac[2][0]), h2u(ac[2][1]), h2u(ac[2][2]), h2u(ac[2][3]));
    }
}

// ============================================================================
// mlp_gemm: y[m,o] = relu(sum_{ki<384} agg[m,ki]*GT[o,ki] + b[o]) + BN stats.
// 64-row M-tile, K-step 64, double-buffered async global_load_lds staging.
// ============================================================================
__global__ __launch_bounds__(256)
void mlp_gemm(const __fp16* __restrict__ agg, const __fp16* __restrict__ GT,
              float* __restrict__ out, int M,
              const float* __restrict__ bias, float* __restrict__ sbuf) {
    __shared__ char smem[49152];
    const int m0 = blockIdx.x * 64;
    const int tid = threadIdx.x;
    const int wave = tid >> 6, lane = tid & 63;
    const int wm0 = wave * 16;
    const int lrow = lane & 15;
    const int kg = lane >> 4;
    const int srow = lane >> 3;
    const int schunk = lane & 7;

    auto STAGE = [&](int buf, int kc) {
        char* base = smem + buf * 24576;
        #pragma unroll
        for (int j = 0; j < 2; ++j) {
            const int rl = wave * 16 + j * 8 + srow;
            const int rg = min(m0 + rl, M - 1);
            gload16(agg + (size_t)rg * 384 + kc * 64 + ((schunk ^ (rl & 7)) << 3),
                    base + (wave * 16 + j * 8) * 128);
        }
        #pragma unroll
        for (int j = 0; j < 4; ++j) {
            const int rl = wave * 32 + j * 8 + srow;
            gload16(GT + (size_t)rl * 384 + kc * 64 + ((schunk ^ (rl & 7)) << 3),
                    base + 8192 + (wave * 32 + j * 8) * 128);
        }
    };

    f32x4 acc[8];
    #pragma unroll
    for (int b = 0; b < 8; ++b) acc[b] = (f32x4){0.f, 0.f, 0.f, 0.f};

    STAGE(0, 0);
    __syncthreads();

    for (int kc = 0; kc < 6; ++kc) {
        const int buf = kc & 1;
        if (kc < 5) STAGE(buf ^ 1, kc + 1);
        const char* Ab = smem + buf * 24576;
        const char* Bb = Ab + 8192;
        f16x8 afr[2];
        #pragma unroll
        for (int ks = 0; ks < 2; ++ks) {
            const int row = wm0 + lrow;
            afr[ks] = *(const f16x8*)(Ab + row * 128 + (((ks * 4 + kg) ^ (row & 7)) << 4));
        }
        #pragma unroll
        for (int nf = 0; nf < 8; ++nf) {
            #pragma unroll
            for (int ks = 0; ks < 2; ++ks) {
                const int row = nf * 16 + lrow;
                f16x8 bfr = *(const f16x8*)(Bb + row * 128 + (((ks * 4 + kg) ^ (row & 7)) << 4));
                acc[nf] = __builtin_amdgcn_mfma_f32_16x16x32_f16(afr[ks], bfr, acc[nf], 0, 0, 0);
            }
        }
        __syncthreads();
    }

    float s[8], s2[8], bv[8];
    #pragma unroll
    for (int nf = 0; nf < 8; ++nf) { s[nf] = 0.f; s2[nf] = 0.f; bv[nf] = bias[nf * 16 + lrow]; }
    #pragma unroll
    for (int nf = 0; nf < 8; ++nf)
        #pragma unroll
        for (int rg = 0; rg < 4; ++rg) {
            const int row = m0 + wm0 + kg * 4 + rg;
            if (row < M) {
                const float v = fmaxf(acc[nf][rg] + bv[nf], 0.f);
                out[(size_t)row * FEAT + nf * 16 + lrow] = v;
                s[nf] += v;
                s2[nf] = fmaf(v, v, s2[nf]);
            }
        }
    #pragma unroll
    for (int nf = 0; nf < 8; ++nf) {
        s[nf]  += __shfl_xor(s[nf], 16);  s[nf]  += __shfl_xor(s[nf], 32);
        s2[nf] += __shfl_xor(s2[nf], 16); s2[nf] += __shfl_xor(s2[nf], 32);
    }
    __syncthreads();
    float* red = (float*)smem;
    if (lane < 16) {
        #pragma unroll
        for (int nf = 0; nf < 8; ++nf) {
            red[wave * 256 + nf * 16 + lane]       = s[nf];
            red[wave * 256 + 128 + nf * 16 + lane] = s2[nf];
        }
    }
    __syncthreads();
    if (tid < 128) {
        const float ss = red[tid] + red[256 + tid] + red[512 + tid] + red[768 + tid];
        const float qq = red[128 + tid] + red[384 + tid] + red[640 + tid] + red[896 + tid];
        float* sb = sbuf + (blockIdx.x & (NSHARD - 1)) * 256;
        atomicAdd(sb + tid, ss);
        atomicAdd(sb + FEAT + tid, qq);
    }
}

// ---- BN normalize (sums the 16 stat shards, derives scale/shift) ----
__global__ void normalize(float* __restrict__ y, const float* __restrict__ sbuf,
                          const float* __restrict__ gamma, const float* __restrict__ beta) {
    __shared__ float sc_s[FEAT], sh_s[FEAT];
    const int t = threadIdx.x;
    if (t < FEAT) {
        float ssum = 0.f, qsum = 0.f;
        #pragma unroll
        for (int sh = 0; sh < NSHARD; ++sh) {
            ssum += sbuf[sh * 256 + t];
            qsum += sbuf[sh * 256 + 128 + t];
        }
        const float mean = ssum / (float)N_NODES;
        const float var  = qsum / (float)N_NODES - mean * mean;
        const float sc   = gamma[t] * rsqrtf(var + BN_EPS);
        sc_s[t] = sc;
        sh_s[t] = beta[t] - mean * sc;
    }
    __syncthreads();
    const int idx = blockIdx.x * blockDim.x + t;
    const int o4 = (idx & 31) * 4;
    float4 v = *(float4*)(y + (size_t)idx * 4);
    const float4 sc = *(const float4*)(sc_s + o4);
    const float4 sh = *(const float4*)(sh_s + o4);
    v.x = fmaf(v.x, sc.x, sh.x);
    v.y = fmaf(v.y, sc.y, sh.y);
    v.z = fmaf(v.z, sc.z, sh.z);
    v.w = fmaf(v.w, sc.w, sh.w);
    *(float4*)(y + (size_t)idx * 4) = v;
}

extern "C" void kernel_launch(void* const* d_in, const int* in_sizes, int n_in,
                              void* d_out, int out_size, void* d_ws, size_t ws_size,
                              hipStream_t stream) {
    const float* feature = (const float*)d_in[0];
    const float* coords  = (const float*)d_in[1];
    const int*   src     = (const int*)d_in[2];
    const int*   dst     = (const int*)d_in[3];
    const int*   order   = (const int*)d_in[4];
    const float* linear  = (const float*)d_in[5];
    const float* attW    = (const float*)d_in[6];
    const float* mlp_w   = (const float*)d_in[7];
    const float* mlp_b   = (const float*)d_in[8];
    const float* gamma   = (const float*)d_in[9];
    const float* beta    = (const float*)d_in[10];
    float* out = (float*)d_out;

    char* p = (char*)d_ws;
    __fp16* fh           = (__fp16*)p;  p += (size_t)N_NODES * FEAT * 2;   // 12.8 MB
    __fp16* agg          = (__fp16*)p;  p += (size_t)N_NODES * 384 * 2;    // 38.4 MB
    __fp16* GT           = (__fp16*)p;  p += (size_t)FEAT * 384 * 2;       // 98 KB
    float4* pk           = (float4*)p;  p += (size_t)N_NODES * 32;         // 1.6 MB
    int*   sord_p        = (int*)p;     p += (size_t)E_EDGES * 4;          // 3.2 MB
    float* att_p         = (float*)p;   p += (size_t)E_EDGES * 4;          // 3.2 MB
    float* invd_p        = (float*)p;   p += (size_t)E_EDGES * 4;          // 3.2 MB
    int2*  bbuf          = (int2*)p;    p += (size_t)NBUK * BCAP * 8;      // 8.0 MB
    int*   cnt           = (int*)p;     p += 200064;
    float* sbuf          = (float*)p;   p += NSHARD * 256 * 4;             // 16 KB
    int*   gcur          = (int*)p;     p += 1024;   // memset covers cnt+sbuf+gcur
    int*   rowptr        = (int*)p;     p += 200064;
    int*   cursor        = (int*)p;     p += 200064;
    int*   bsum          = (int*)p;     p += 256;

    hipMemsetAsync(cnt, 0, 200064 + NSHARD * 256 * 4 + 1024, stream);

    const int MB = (N_NODES + 63) / 64;          // 782
    const int AB = (E_EDGES + 2047) / 2048;      // 391

    g_cast<<<NWB_BLKS + FEAT, 256, 0, stream>>>(feature, coords, attW,
                                                mlp_w, linear, fh, pk, GT);

    bucketA<<<AB, 256, 0, stream>>>(src, dst, order, cnt, gcur, bbuf);
    scan1<<<NB1, 256, 0, stream>>>(cnt, rowptr, bsum);
    scan3<<<(N_NODES + 255) / 256, 256, 0, stream>>>(rowptr, cursor, bsum);
    bucketB<<<NBUK * 8, 256, 0, stream>>>(gcur, bbuf, pk, cursor, sord_p, att_p, invd_p);

    segagg<<<NWB_BLKS, 256, 0, stream>>>(sord_p, att_p, invd_p, rowptr, fh, agg);

    mlp_gemm<<<MB, 256, 0, stream>>>(agg, GT, out, N_NODES, mlp_b, sbuf);
    normalize<<<(N_NODES * 32) / 256, 256, 0, stream>>>(out, sbuf, gamma, beta);
}

// Round 18
// 177.052 us; speedup vs baseline: 1.0821x; 1.0821x over previous
//
#include <hip/hip_runtime.h>

#define N_NODES 50000
#define E_EDGES 800000
#define FEAT    128
#define KORD    3
#define BN_EPS  1e-5f
#define NB1     49          // ceil(50000/1024) scan blocks
#define NBUK    49          // coarse buckets (dst >> 10)
#define BCAP    20480       // bucket capacity
#define NSHARD  16          // BN-stats atomic shards
#define NSEG    32          // bucketB segments per bucket
#define NWB_BLKS 12500      // (N_NODES*64)/256

typedef __fp16 f16x2 __attribute__((ext_vector_type(2)));
typedef __fp16 f16x8 __attribute__((ext_vector_type(8)));
typedef __attribute__((ext_vector_type(4))) float f32x4;

__device__ __forceinline__ unsigned h2u(f16x2 h) { union { f16x2 h; unsigned u; } c; c.h = h; return c.u; }
__device__ __forceinline__ f16x2 u2h(unsigned u) { union { unsigned u; f16x2 h; } c; c.u = u; return c.h; }

// async global->LDS, 16B per lane (lane lands at ldsbase + lane*16)
__device__ __forceinline__ void gload16(const void* g, void* l) {
    __builtin_amdgcn_global_load_lds(
        (const __attribute__((address_space(1))) unsigned int*)g,
        (__attribute__((address_space(3))) unsigned int*)l, 16, 0, 0);
}

// ---- per node: feature->f16, pack {coords, g=attW@f}; tail blocks: fold
//      GT[o][k*128+i] = sum_j L[k][i][j]*W[o][j]  (gprep merged) ----
__global__ void g_cast(const float* __restrict__ feat,
                       const float* __restrict__ coords,
                       const float* __restrict__ attW,
                       const float* __restrict__ W,
                       const float* __restrict__ L,
                       __fp16* __restrict__ fh,
                       float4* __restrict__ pk,
                       __fp16* __restrict__ GT) {
    __shared__ float wrow[FEAT];
    if (blockIdx.x >= NWB_BLKS) {            // gprep tail blocks (128)
        const int o = blockIdx.x - NWB_BLKS;
        const int i = threadIdx.x;
        if (i < FEAT) wrow[i] = W[o * FEAT + i];
        __syncthreads();
        if (i < FEAT) {
            #pragma unroll
            for (int k = 0; k < KORD; ++k) {
                const float* lp = L + ((size_t)k * FEAT + i) * FEAT;
                float acc = 0.f;
                #pragma unroll 8
                for (int j = 0; j < FEAT; ++j) acc = fmaf(lp[j], wrow[j], acc);
                GT[(size_t)o * 384 + k * FEAT + i] = (__fp16)acc;
            }
        }
        return;
    }
    const int node = (blockIdx.x * blockDim.x + threadIdx.x) >> 6;
    const int lane = threadIdx.x & 63;
    if (node >= N_NODES) return;
    const float2 f = *(const float2*)(feat + (size_t)node * FEAT + lane * 2);
    *(f16x2*)(fh + (size_t)node * FEAT + lane * 2) = __builtin_amdgcn_cvt_pkrtz(f.x, f.y);
    float gg[3];
    #pragma unroll
    for (int j = 0; j < 3; ++j) {
        float p = f.x * attW[j * FEAT + lane * 2] + f.y * attW[j * FEAT + lane * 2 + 1];
        #pragma unroll
        for (int off = 32; off; off >>= 1) p += __shfl_xor(p, off);
        gg[j] = p;
    }
    if (lane == 0) {
        const float c0 = coords[node * 3 + 0], c1 = coords[node * 3 + 1], c2 = coords[node * 3 + 2];
        pk[2 * node]     = make_float4(c0, c1, c2, gg[0]);
        pk[2 * node + 1] = make_float4(gg[1], gg[2], 0.f, 0.f);
    }
}

// ============ CSR build ============
__global__ __launch_bounds__(256)
void bucketA(const int* __restrict__ src, const int* __restrict__ dst,
             const int* __restrict__ order,
             int* __restrict__ cnt, int* __restrict__ gcur, int2* __restrict__ bbuf) {
    __shared__ int lcnt[NBUK];
    __shared__ int lbase[NBUK];
    const int tid = threadIdx.x;
    if (tid < NBUK) lcnt[tid] = 0;
    __syncthreads();
    const int e0 = blockIdx.x * 2048;
    int b[8], r[8], so[8], dd[8];
    #pragma unroll
    for (int i = 0; i < 8; ++i) {
        const int e = e0 + i * 256 + tid;
        if (e < E_EDGES) {
            dd[i] = dst[e];
            so[i] = (order[e] << 16) | src[e];
            b[i] = dd[i] >> 10;
            r[i] = atomicAdd(&lcnt[b[i]], 1);
            atomicAdd(cnt + dd[i], 1);
        } else b[i] = -1;
    }
    __syncthreads();
    if (tid < NBUK) lbase[tid] = atomicAdd(&gcur[tid], lcnt[tid]);
    __syncthreads();
    #pragma unroll
    for (int i = 0; i < 8; ++i)
        if (b[i] >= 0)
            bbuf[(size_t)b[i] * BCAP + lbase[b[i]] + r[i]] = make_int2(so[i], dd[i]);
}

__global__ __launch_bounds__(256)
void scan1(const int* __restrict__ cnt, int* __restrict__ rowptr, int* __restrict__ bsum) {
    __shared__ int lds[256];
    const int b = blockIdx.x, t = threadIdx.x;
    const int base = b * 1024 + t * 4;
    int v[4];
    #pragma unroll
    for (int i = 0; i < 4; ++i) v[i] = (base + i < N_NODES) ? cnt[base + i] : 0;
    lds[t] = v[0] + v[1] + v[2] + v[3];
    __syncthreads();
    for (int off = 1; off < 256; off <<= 1) {
        const int u = (t >= off) ? lds[t - off] : 0;
        __syncthreads();
        lds[t] += u;
        __syncthreads();
    }
    int excl = t ? lds[t - 1] : 0;
    if (t == 255) bsum[b] = lds[255];
    #pragma unroll
    for (int i = 0; i < 4; ++i) {
        if (base + i < N_NODES) rowptr[base + i] = excl;
        excl += v[i];
    }
}

// ---- scan3 (scan2 folded: wave 0 rescans the 49 block sums) ----
__global__ void scan3(int* __restrict__ rowptr, int* __restrict__ cursor,
                      const int* __restrict__ bsum) {
    __shared__ int boff_s[64];
    const int t = threadIdx.x;
    if (t < 64) {
        const int v = (t < NB1) ? bsum[t] : 0;
        int incl = v;
        #pragma unroll
        for (int off = 1; off < 64; off <<= 1) {
            const int u = __shfl_up(incl, off);
            if (t >= off) incl += u;
        }
        boff_s[t] = incl - v;
    }
    __syncthreads();
    const int i = blockIdx.x * 256 + t;
    if (i < N_NODES) {
        const int v = rowptr[i] + boff_s[i >> 10];
        rowptr[i] = v;
        cursor[i] = v;
    }
    if (i == 0) rowptr[N_NODES] = E_EDGES;
}

// ---- bucketB: CSR scatter + per-edge att/invdist, ONE packed 16B store ----
__global__ void bucketB(const int* __restrict__ gcur, const int2* __restrict__ bbuf,
                        const float4* __restrict__ pk,
                        int* __restrict__ cursor, int4* __restrict__ edata) {
    const int b = blockIdx.x / NSEG;
    const int seg = blockIdx.x % NSEG;
    const int n = gcur[b];
    const int lo = (int)((long)n * seg / NSEG), hi = (int)((long)n * (seg + 1) / NSEG);
    for (int i = lo + (int)threadIdx.x; i < hi; i += 256) {
        const int2 ent = bbuf[(size_t)b * BCAP + i];
        const int s = ent.x & 0xFFFF;
        const int d = ent.y;
        const float4 a0 = pk[2 * s], a1 = pk[2 * s + 1], c0 = pk[2 * d];
        const float dx = a0.x - c0.x, dy = a0.y - c0.y, dz = a0.z - c0.z;
        const float att  = dx * a0.w + dy * a1.x + dz * a1.y;
        const float invd = 1.f / (dx * dx + dy * dy + dz * dz + 1.f);
        const int pos = atomicAdd(cursor + d, 1);
        edata[pos] = make_int4(ent.x, __float_as_int(att), __float_as_int(invd), 0);
    }
}

// ---- segment softmax + per-order gather-aggregate (stream + fh gather) ----
__global__ void segagg(const int4* __restrict__ edata,
                       const int* __restrict__ rowptr,
                       const __fp16* __restrict__ fh,
                       __fp16* __restrict__ agg) {
    __shared__ uint4 stash[4][64];
    const int node = (blockIdx.x * blockDim.x + threadIdx.x) >> 6;
    const int lane = threadIdx.x & 63;
    const int wid  = threadIdx.x >> 6;
    if (node >= N_NODES) return;
    const int beg = rowptr[node], end = rowptr[node + 1];

    // phase 1: online (m,s) over contiguous edata; cache chunk-0 record
    int4 e0c = make_int4(0, 0xFF800000, 0, 0);   // att = -inf
    float m = -1e30f, s = 0.f;
    int nch = 0;
    for (int cb = beg; cb < end; cb += 64, ++nch) {
        const int p = cb + lane;
        float a = -1e30f;
        if (p < end) {
            const int4 e = edata[p];
            a = __int_as_float(e.y);
            if (nch == 0) e0c = e;
        }
        const float mn = fmaxf(m, a);
        s = s * __expf(m - mn) + ((p < end) ? __expf(a - mn) : 0.f);
        m = mn;
    }
    #pragma unroll
    for (int off = 32; off; off >>= 1) {
        const float mo = __shfl_xor(m, off), so_ = __shfl_xor(s, off);
        const float mn = fmaxf(m, mo);
        s = s * __expf(m - mn) + so_ * __expf(mo - mn);
        m = mn;
    }
    const float inv_s = s > 0.f ? 1.f / s : 0.f;

    // phase 2: 4-edge groups, 2 gathers in flight
    const int grp = lane >> 4;
    const int fl  = lane & 15;
    f16x2 ac[3][4];
    #pragma unroll
    for (int o = 0; o < 3; ++o)
        #pragma unroll
        for (int q = 0; q < 4; ++q) ac[o][q] = (f16x2){0, 0};

    int ch = 0;
    for (int cb = beg; cb < end; cb += 64, ++ch) {
        const int p = cb + lane;
        float wl = 0.f; int so = 0;
        if (p < end) {
            const int4 e = (ch == 0) ? e0c : edata[p];
            wl = __expf(__int_as_float(e.y) - m) * inv_s * __int_as_float(e.z);
            so = e.x;
        }
        const int k = so >> 16;
        const __fp16 wh = (__fp16)wl;
        f16x2 w2; w2.x = wh; w2.y = wh;
        const unsigned uw = h2u(w2);
        stash[wid][lane] = make_uint4(k == 0 ? uw : 0u, k == 1 ? uw : 0u,
                                      k == 2 ? uw : 0u, (unsigned)(so & 0xFFFF));
        const int ne = min(64, end - cb);
        const uint4* st = stash[wid];
        for (int t = 0; t < ne; t += 8) {
            const uint4 e1 = st[t + grp];
            const uint4 e2 = st[t + 4 + grp];
            const uint4 v1 = *(const uint4*)(fh + ((size_t)e1.w << 7) + fl * 8);
            const uint4 v2 = *(const uint4*)(fh + ((size_t)e2.w << 7) + fl * 8);
            {
                const f16x2 w0 = u2h(e1.x), w1 = u2h(e1.y), w2v = u2h(e1.z);
                const f16x2 va = u2h(v1.x), vb = u2h(v1.y), vc = u2h(v1.z), vd = u2h(v1.w);
                ac[0][0] = __builtin_elementwise_fma(va, w0, ac[0][0]);
                ac[0][1] = __builtin_elementwise_fma(vb, w0, ac[0][1]);
                ac[0][2] = __builtin_elementwise_fma(vc, w0, ac[0][2]);
                ac[0][3] = __builtin_elementwise_fma(vd, w0, ac[0][3]);
                ac[1][0] = __builtin_elementwise_fma(va, w1, ac[1][0]);
                ac[1][1] = __builtin_elementwise_fma(vb, w1, ac[1][1]);
                ac[1][2] = __builtin_elementwise_fma(vc, w1, ac[1][2]);
                ac[1][3] = __builtin_elementwise_fma(vd, w1, ac[1][3]);
                ac[2][0] = __builtin_elementwise_fma(va, w2v, ac[2][0]);
                ac[2][1] = __builtin_elementwise_fma(vb, w2v, ac[2][1]);
                ac[2][2] = __builtin_elementwise_fma(vc, w2v, ac[2][2]);
                ac[2][3] = __builtin_elementwise_fma(vd, w2v, ac[2][3]);
            }
            {
                const f16x2 w0 = u2h(e2.x), w1 = u2h(e2.y), w2v = u2h(e2.z);
                const f16x2 va = u2h(v2.x), vb = u2h(v2.y), vc = u2h(v2.z), vd = u2h(v2.w);
                ac[0][0] = __builtin_elementwise_fma(va, w0, ac[0][0]);
                ac[0][1] = __builtin_elementwise_fma(vb, w0, ac[0][1]);
                ac[0][2] = __builtin_elementwise_fma(vc, w0, ac[0][2]);
                ac[0][3] = __builtin_elementwise_fma(vd, w0, ac[0][3]);
                ac[1][0] = __builtin_elementwise_fma(va, w1, ac[1][0]);
                ac[1][1] = __builtin_elementwise_fma(vb, w1, ac[1][1]);
                ac[1][2] = __builtin_elementwise_fma(vc, w1, ac[1][2]);
                ac[1][3] = __builtin_elementwise_fma(vd, w1, ac[1][3]);
                ac[2][0] = __builtin_elementwise_fma(va, w2v, ac[2][0]);
                ac[2][1] = __builtin_elementwise_fma(vb, w2v, ac[2][1]);
                ac[2][2] = __builtin_elementwise_fma(vc, w2v, ac[2][2]);
                ac[2][3] = __builtin_elementwise_fma(vd, w2v, ac[2][3]);
            }
        }
    }
    #pragma unroll
    for (int o = 0; o < 3; ++o)
        #pragma unroll
        for (int q = 0; q < 4; ++q) {
            ac[o][q] = ac[o][q] + u2h(__shfl_xor((int)h2u(ac[o][q]), 16));
            ac[o][q] = ac[o][q] + u2h(__shfl_xor((int)h2u(ac[o][q]), 32));
        }
    if (lane < 16) {
        __fp16* row = agg + (size_t)node * 384 + fl * 8;
        *(uint4*)(row)       = make_uint4(h2u(ac[0][0]), h2u(ac[0][1]), h2u(ac[0][2]), h2u(ac[0][3]));
        *(uint4*)(row + 128) = make_uint4(h2u(ac[1][0]), h2u(ac[1][1]), h2u(ac[1][2]), h2u(ac[1][3]));
        *(uint4*)(row + 256) = make_uint4(h2u(ac[2][0]), h2u(ac[2][1]), h2u(ac[2][2]), h2u(ac[2][3]));
    }
}

// ============================================================================
// mlp_gemm: y[m,o] = relu(sum_{ki<384} agg[m,ki]*GT[o,ki] + b[o]) + BN stats.
// 64-row M-tile, K-step 64, double-buffered async global_load_lds staging.
// ============================================================================
__global__ __launch_bounds__(256)
void mlp_gemm(const __fp16* __restrict__ agg, const __fp16* __restrict__ GT,
              float* __restrict__ out, int M,
              const float* __restrict__ bias, float* __restrict__ sbuf) {
    __shared__ char smem[49152];
    const int m0 = blockIdx.x * 64;
    const int tid = threadIdx.x;
    const int wave = tid >> 6, lane = tid & 63;
    const int wm0 = wave * 16;
    const int lrow = lane & 15;
    const int kg = lane >> 4;
    const int srow = lane >> 3;
    const int schunk = lane & 7;

    auto STAGE = [&](int buf, int kc) {
        char* base = smem + buf * 24576;
        #pragma unroll
        for (int j = 0; j < 2; ++j) {
            const int rl = wave * 16 + j * 8 + srow;
            const int rg = min(m0 + rl, M - 1);
            gload16(agg + (size_t)rg * 384 + kc * 64 + ((schunk ^ (rl & 7)) << 3),
                    base + (wave * 16 + j * 8) * 128);
        }
        #pragma unroll
        for (int j = 0; j < 4; ++j) {
            const int rl = wave * 32 + j * 8 + srow;
            gload16(GT + (size_t)rl * 384 + kc * 64 + ((schunk ^ (rl & 7)) << 3),
                    base + 8192 + (wave * 32 + j * 8) * 128);
        }
    };

    f32x4 acc[8];
    #pragma unroll
    for (int b = 0; b < 8; ++b) acc[b] = (f32x4){0.f, 0.f, 0.f, 0.f};

    STAGE(0, 0);
    __syncthreads();

    for (int kc = 0; kc < 6; ++kc) {
        const int buf = kc & 1;
        if (kc < 5) STAGE(buf ^ 1, kc + 1);
        const char* Ab = smem + buf * 24576;
        const char* Bb = Ab + 8192;
        f16x8 afr[2];
        #pragma unroll
        for (int ks = 0; ks < 2; ++ks) {
            const int row = wm0 + lrow;
            afr[ks] = *(const f16x8*)(Ab + row * 128 + (((ks * 4 + kg) ^ (row & 7)) << 4));
        }
        #pragma unroll
        for (int nf = 0; nf < 8; ++nf) {
            #pragma unroll
            for (int ks = 0; ks < 2; ++ks) {
                const int row = nf * 16 + lrow;
                f16x8 bfr = *(const f16x8*)(Bb + row * 128 + (((ks * 4 + kg) ^ (row & 7)) << 4));
                acc[nf] = __builtin_amdgcn_mfma_f32_16x16x32_f16(afr[ks], bfr, acc[nf], 0, 0, 0);
            }
        }
        __syncthreads();
    }

    float s[8], s2[8], bv[8];
    #pragma unroll
    for (int nf = 0; nf < 8; ++nf) { s[nf] = 0.f; s2[nf] = 0.f; bv[nf] = bias[nf * 16 + lrow]; }
    #pragma unroll
    for (int nf = 0; nf < 8; ++nf)
        #pragma unroll
        for (int rg = 0; rg < 4; ++rg) {
            const int row = m0 + wm0 + kg * 4 + rg;
            if (row < M) {
                const float v = fmaxf(acc[nf][rg] + bv[nf], 0.f);
                out[(size_t)row * FEAT + nf * 16 + lrow] = v;
                s[nf] += v;
                s2[nf] = fmaf(v, v, s2[nf]);
            }
        }
    #pragma unroll
    for (int nf = 0; nf < 8; ++nf) {
        s[nf]  += __shfl_xor(s[nf], 16);  s[nf]  += __shfl_xor(s[nf], 32);
        s2[nf] += __shfl_xor(s2[nf], 16); s2[nf] += __shfl_xor(s2[nf], 32);
    }
    __syncthreads();
    float* red = (float*)smem;
    if (lane < 16) {
        #pragma unroll
        for (int nf = 0; nf < 8; ++nf) {
            red[wave * 256 + nf * 16 + lane]       = s[nf];
            red[wave * 256 + 128 + nf * 16 + lane] = s2[nf];
        }
    }
    __syncthreads();
    if (tid < 128) {
        const float ss = red[tid] + red[256 + tid] + red[512 + tid] + red[768 + tid];
        const float qq = red[128 + tid] + red[384 + tid] + red[640 + tid] + red[896 + tid];
        float* sb = sbuf + (blockIdx.x & (NSHARD - 1)) * 256;
        atomicAdd(sb + tid, ss);
        atomicAdd(sb + FEAT + tid, qq);
    }
}

// ---- BN normalize (sums the 16 stat shards, derives scale/shift) ----
__global__ void normalize(float* __restrict__ y, const float* __restrict__ sbuf,
                          const float* __restrict__ gamma, const float* __restrict__ beta) {
    __shared__ float sc_s[FEAT], sh_s[FEAT];
    const int t = threadIdx.x;
    if (t < FEAT) {
        float ssum = 0.f, qsum = 0.f;
        #pragma unroll
        for (int sh = 0; sh < NSHARD; ++sh) {
            ssum += sbuf[sh * 256 + t];
            qsum += sbuf[sh * 256 + 128 + t];
        }
        const float mean = ssum / (float)N_NODES;
        const float var  = qsum / (float)N_NODES - mean * mean;
        const float sc   = gamma[t] * rsqrtf(var + BN_EPS);
        sc_s[t] = sc;
        sh_s[t] = beta[t] - mean * sc;
    }
    __syncthreads();
    const int idx = blockIdx.x * blockDim.x + t;
    const int o4 = (idx & 31) * 4;
    float4 v = *(float4*)(y + (size_t)idx * 4);
    const float4 sc = *(const float4*)(sc_s + o4);
    const float4 sh = *(const float4*)(sh_s + o4);
    v.x = fmaf(v.x, sc.x, sh.x);
    v.y = fmaf(v.y, sc.y, sh.y);
    v.z = fmaf(v.z, sc.z, sh.z);
    v.w = fmaf(v.w, sc.w, sh.w);
    *(float4*)(y + (size_t)idx * 4) = v;
}

extern "C" void kernel_launch(void* const* d_in, const int* in_sizes, int n_in,
                              void* d_out, int out_size, void* d_ws, size_t ws_size,
                              hipStream_t stream) {
    const float* feature = (const float*)d_in[0];
    const float* coords  = (const float*)d_in[1];
    const int*   src     = (const int*)d_in[2];
    const int*   dst     = (const int*)d_in[3];
    const int*   order   = (const int*)d_in[4];
    const float* linear  = (const float*)d_in[5];
    const float* attW    = (const float*)d_in[6];
    const float* mlp_w   = (const float*)d_in[7];
    const float* mlp_b   = (const float*)d_in[8];
    const float* gamma   = (const float*)d_in[9];
    const float* beta    = (const float*)d_in[10];
    float* out = (float*)d_out;

    char* p = (char*)d_ws;
    __fp16* fh           = (__fp16*)p;  p += (size_t)N_NODES * FEAT * 2;   // 12.8 MB
    __fp16* agg          = (__fp16*)p;  p += (size_t)N_NODES * 384 * 2;    // 38.4 MB
    __fp16* GT           = (__fp16*)p;  p += (size_t)FEAT * 384 * 2;       // 98 KB
    float4* pk           = (float4*)p;  p += (size_t)N_NODES * 32;         // 1.6 MB
    int4*  edata         = (int4*)p;    p += (size_t)E_EDGES * 16;         // 12.8 MB
    int2*  bbuf          = (int2*)p;    p += (size_t)NBUK * BCAP * 8;      // 8.0 MB
    int*   cnt           = (int*)p;     p += 200064;
    float* sbuf          = (float*)p;   p += NSHARD * 256 * 4;             // 16 KB
    int*   gcur          = (int*)p;     p += 1024;   // memset covers cnt+sbuf+gcur
    int*   rowptr        = (int*)p;     p += 200064;
    int*   cursor        = (int*)p;     p += 200064;
    int*   bsum          = (int*)p;     p += 256;

    hipMemsetAsync(cnt, 0, 200064 + NSHARD * 256 * 4 + 1024, stream);

    const int MB = (N_NODES + 63) / 64;          // 782
    const int AB = (E_EDGES + 2047) / 2048;      // 391

    g_cast<<<NWB_BLKS + FEAT, 256, 0, stream>>>(feature, coords, attW,
                                                mlp_w, linear, fh, pk, GT);

    bucketA<<<AB, 256, 0, stream>>>(src, dst, order, cnt, gcur, bbuf);
    scan1<<<NB1, 256, 0, stream>>>(cnt, rowptr, bsum);
    scan3<<<(N_NODES + 255) / 256, 256, 0, stream>>>(rowptr, cursor, bsum);
    bucketB<<<NBUK * NSEG, 256, 0, stream>>>(gcur, bbuf, pk, cursor, edata);

    segagg<<<NWB_BLKS, 256, 0, stream>>>(edata, rowptr, fh, agg);

    mlp_gemm<<<MB, 256, 0, stream>>>(agg, GT, out, N_NODES, mlp_b, sbuf);
    normalize<<<(N_NODES * 32) / 256, 256, 0, stream>>>(out, sbuf, gamma, beta);
}

// Round 19
// 172.093 us; speedup vs baseline: 1.1133x; 1.0288x over previous
//
#include <hip/hip_runtime.h>

#define N_NODES 50000
#define E_EDGES 800000
#define FEAT    128
#define KORD    3
#define BN_EPS  1e-5f
#define NB1     49          // ceil(50000/1024) scan blocks
#define NBUK    49          // coarse buckets (dst >> 10)
#define BCAP    20480       // bucket capacity
#define NSHARD  16          // BN-stats atomic shards
#define NSEG    32          // bucketB segments per bucket
#define NWB_BLKS 12500      // (N_NODES*64)/256
#define NZERO   54368       // ints to zero: cnt(50016) + sbuf(4096) + gcur(256)

typedef __fp16 f16x2 __attribute__((ext_vector_type(2)));
typedef __fp16 f16x8 __attribute__((ext_vector_type(8)));
typedef __attribute__((ext_vector_type(4))) float f32x4;

__device__ __forceinline__ unsigned h2u(f16x2 h) { union { f16x2 h; unsigned u; } c; c.h = h; return c.u; }
__device__ __forceinline__ f16x2 u2h(unsigned u) { union { unsigned u; f16x2 h; } c; c.u = u; return c.h; }

// async global->LDS, 16B per lane (lane lands at ldsbase + lane*16)
__device__ __forceinline__ void gload16(const void* g, void* l) {
    __builtin_amdgcn_global_load_lds(
        (const __attribute__((address_space(1))) unsigned int*)g,
        (__attribute__((address_space(3))) unsigned int*)l, 16, 0, 0);
}

// ---- per node: feature->f16, pack {coords, g=attW@f}; zero cnt/sbuf/gcur;
//      tail blocks: fold GT[o][k*128+i] = sum_j L[k][i][j]*W[o][j] ----
__global__ void g_cast(const float* __restrict__ feat,
                       const float* __restrict__ coords,
                       const float* __restrict__ attW,
                       const float* __restrict__ W,
                       const float* __restrict__ L,
                       __fp16* __restrict__ fh,
                       float4* __restrict__ pk,
                       __fp16* __restrict__ GT,
                       int* __restrict__ zbase) {
    __shared__ float wrow[FEAT];
    const int gtid = blockIdx.x * 256 + threadIdx.x;
    if (gtid < NZERO) zbase[gtid] = 0;       // replaces 41us fillBuffer kernel
    if (blockIdx.x >= NWB_BLKS) {            // gprep tail blocks (128)
        const int o = blockIdx.x - NWB_BLKS;
        const int i = threadIdx.x;
        if (i < FEAT) wrow[i] = W[o * FEAT + i];
        __syncthreads();
        if (i < FEAT) {
            #pragma unroll
            for (int k = 0; k < KORD; ++k) {
                const float* lp = L + ((size_t)k * FEAT + i) * FEAT;
                float acc = 0.f;
                #pragma unroll 8
                for (int j = 0; j < FEAT; ++j) acc = fmaf(lp[j], wrow[j], acc);
                GT[(size_t)o * 384 + k * FEAT + i] = (__fp16)acc;
            }
        }
        return;
    }
    const int node = gtid >> 6;
    const int lane = threadIdx.x & 63;
    if (node >= N_NODES) return;
    const float2 f = *(const float2*)(feat + (size_t)node * FEAT + lane * 2);
    *(f16x2*)(fh + (size_t)node * FEAT + lane * 2) = __builtin_amdgcn_cvt_pkrtz(f.x, f.y);
    float gg[3];
    #pragma unroll
    for (int j = 0; j < 3; ++j) {
        float p = f.x * attW[j * FEAT + lane * 2] + f.y * attW[j * FEAT + lane * 2 + 1];
        #pragma unroll
        for (int off = 32; off; off >>= 1) p += __shfl_xor(p, off);
        gg[j] = p;
    }
    if (lane == 0) {
        const float c0 = coords[node * 3 + 0], c1 = coords[node * 3 + 1], c2 = coords[node * 3 + 2];
        pk[2 * node]     = make_float4(c0, c1, c2, gg[0]);
        pk[2 * node + 1] = make_float4(gg[1], gg[2], 0.f, 0.f);
    }
}

// ============ CSR build ============
// per-wave LDS counters: quarters same-address LDS-atomic contention
__global__ __launch_bounds__(256)
void bucketA(const int* __restrict__ src, const int* __restrict__ dst,
             const int* __restrict__ order,
             int* __restrict__ cnt, int* __restrict__ gcur, int2* __restrict__ bbuf) {
    __shared__ int lcnt[4][NBUK];
    __shared__ int wbase[4][NBUK];
    const int tid = threadIdx.x;
    const int wid = tid >> 6;
    if (tid < NBUK) {
        lcnt[0][tid] = 0; lcnt[1][tid] = 0; lcnt[2][tid] = 0; lcnt[3][tid] = 0;
    }
    __syncthreads();
    const int e0 = blockIdx.x * 2048;
    int b[8], r[8], so[8], dd[8];
    #pragma unroll
    for (int i = 0; i < 8; ++i) {
        const int e = e0 + i * 256 + tid;
        if (e < E_EDGES) {
            dd[i] = dst[e];
            so[i] = (order[e] << 16) | src[e];
            b[i] = dd[i] >> 10;
            r[i] = atomicAdd(&lcnt[wid][b[i]], 1);
            atomicAdd(cnt + dd[i], 1);
        } else b[i] = -1;
    }
    __syncthreads();
    if (tid < NBUK) {
        const int w0 = lcnt[0][tid], w1 = lcnt[1][tid], w2 = lcnt[2][tid], w3 = lcnt[3][tid];
        const int base = atomicAdd(gcur + tid, w0 + w1 + w2 + w3);
        wbase[0][tid] = base;
        wbase[1][tid] = base + w0;
        wbase[2][tid] = base + w0 + w1;
        wbase[3][tid] = base + w0 + w1 + w2;
    }
    __syncthreads();
    #pragma unroll
    for (int i = 0; i < 8; ++i)
        if (b[i] >= 0)
            bbuf[(size_t)b[i] * BCAP + wbase[wid][b[i]] + r[i]] = make_int2(so[i], dd[i]);
}

__global__ __launch_bounds__(256)
void scan1(const int* __restrict__ cnt, int* __restrict__ rowptr, int* __restrict__ bsum) {
    __shared__ int lds[256];
    const int b = blockIdx.x, t = threadIdx.x;
    const int base = b * 1024 + t * 4;
    int v[4];
    #pragma unroll
    for (int i = 0; i < 4; ++i) v[i] = (base + i < N_NODES) ? cnt[base + i] : 0;
    lds[t] = v[0] + v[1] + v[2] + v[3];
    __syncthreads();
    for (int off = 1; off < 256; off <<= 1) {
        const int u = (t >= off) ? lds[t - off] : 0;
        __syncthreads();
        lds[t] += u;
        __syncthreads();
    }
    int excl = t ? lds[t - 1] : 0;
    if (t == 255) bsum[b] = lds[255];
    #pragma unroll
    for (int i = 0; i < 4; ++i) {
        if (base + i < N_NODES) rowptr[base + i] = excl;
        excl += v[i];
    }
}

// ---- scan3 (scan2 folded: wave 0 rescans the 49 block sums) ----
__global__ void scan3(int* __restrict__ rowptr, int* __restrict__ cursor,
                      const int* __restrict__ bsum) {
    __shared__ int boff_s[64];
    const int t = threadIdx.x;
    if (t < 64) {
        const int v = (t < NB1) ? bsum[t] : 0;
        int incl = v;
        #pragma unroll
        for (int off = 1; off < 64; off <<= 1) {
            const int u = __shfl_up(incl, off);
            if (t >= off) incl += u;
        }
        boff_s[t] = incl - v;
    }
    __syncthreads();
    const int i = blockIdx.x * 256 + t;
    if (i < N_NODES) {
        const int v = rowptr[i] + boff_s[i >> 10];
        rowptr[i] = v;
        cursor[i] = v;
    }
    if (i == 0) rowptr[N_NODES] = E_EDGES;
}

// ---- bucketB: CSR scatter + per-edge att/invdist, ONE packed 16B store ----
__global__ void bucketB(const int* __restrict__ gcur, const int2* __restrict__ bbuf,
                        const float4* __restrict__ pk,
                        int* __restrict__ cursor, int4* __restrict__ edata) {
    const int b = blockIdx.x / NSEG;
    const int seg = blockIdx.x % NSEG;
    const int n = gcur[b];
    const int lo = (int)((long)n * seg / NSEG), hi = (int)((long)n * (seg + 1) / NSEG);
    for (int i = lo + (int)threadIdx.x; i < hi; i += 256) {
        const int2 ent = bbuf[(size_t)b * BCAP + i];
        const int s = ent.x & 0xFFFF;
        const int d = ent.y;
        const float4 a0 = pk[2 * s], a1 = pk[2 * s + 1], c0 = pk[2 * d];
        const float dx = a0.x - c0.x, dy = a0.y - c0.y, dz = a0.z - c0.z;
        const float att  = dx * a0.w + dy * a1.x + dz * a1.y;
        const float invd = 1.f / (dx * dx + dy * dy + dz * dz + 1.f);
        const int pos = atomicAdd(cursor + d, 1);
        edata[pos] = make_int4(ent.x, __float_as_int(att), __float_as_int(invd), 0);
    }
}

// ---- segment softmax + per-order gather-aggregate (stream + fh gather) ----
__global__ void segagg(const int4* __restrict__ edata,
                       const int* __restrict__ rowptr,
                       const __fp16* __restrict__ fh,
                       __fp16* __restrict__ agg) {
    __shared__ uint4 stash[4][64];
    const int node = (blockIdx.x * blockDim.x + threadIdx.x) >> 6;
    const int lane = threadIdx.x & 63;
    const int wid  = threadIdx.x >> 6;
    if (node >= N_NODES) return;
    const int beg = rowptr[node], end = rowptr[node + 1];

    // phase 1: online (m,s) over contiguous edata; cache chunk-0 record
    int4 e0c = make_int4(0, 0xFF800000, 0, 0);   // att = -inf
    float m = -1e30f, s = 0.f;
    int nch = 0;
    for (int cb = beg; cb < end; cb += 64, ++nch) {
        const int p = cb + lane;
        float a = -1e30f;
        if (p < end) {
            const int4 e = edata[p];
            a = __int_as_float(e.y);
            if (nch == 0) e0c = e;
        }
        const float mn = fmaxf(m, a);
        s = s * __expf(m - mn) + ((p < end) ? __expf(a - mn) : 0.f);
        m = mn;
    }
    #pragma unroll
    for (int off = 32; off; off >>= 1) {
        const float mo = __shfl_xor(m, off), so_ = __shfl_xor(s, off);
        const float mn = fmaxf(m, mo);
        s = s * __expf(m - mn) + so_ * __expf(mo - mn);
        m = mn;
    }
    const float inv_s = s > 0.f ? 1.f / s : 0.f;

    // phase 2: 4-edge groups, 2 gathers in flight
    const int grp = lane >> 4;
    const int fl  = lane & 15;
    f16x2 ac[3][4];
    #pragma unroll
    for (int o = 0; o < 3; ++o)
        #pragma unroll
        for (int q = 0; q < 4; ++q) ac[o][q] = (f16x2){0, 0};

    int ch = 0;
    for (int cb = beg; cb < end; cb += 64, ++ch) {
        const int p = cb + lane;
        float wl = 0.f; int so = 0;
        if (p < end) {
            const int4 e = (ch == 0) ? e0c : edata[p];
            wl = __expf(__int_as_float(e.y) - m) * inv_s * __int_as_float(e.z);
            so = e.x;
        }
        const int k = so >> 16;
        const __fp16 wh = (__fp16)wl;
        f16x2 w2; w2.x = wh; w2.y = wh;
        const unsigned uw = h2u(w2);
        stash[wid][lane] = make_uint4(k == 0 ? uw : 0u, k == 1 ? uw : 0u,
                                      k == 2 ? uw : 0u, (unsigned)(so & 0xFFFF));
        const int ne = min(64, end - cb);
        const uint4* st = stash[wid];
        for (int t = 0; t < ne; t += 8) {
            const uint4 e1 = st[t + grp];
            const uint4 e2 = st[t + 4 + grp];
            const uint4 v1 = *(const uint4*)(fh + ((size_t)e1.w << 7) + fl * 8);
            const uint4 v2 = *(const uint4*)(fh + ((size_t)e2.w << 7) + fl * 8);
            {
                const f16x2 w0 = u2h(e1.x), w1 = u2h(e1.y), w2v = u2h(e1.z);
                const f16x2 va = u2h(v1.x), vb = u2h(v1.y), vc = u2h(v1.z), vd = u2h(v1.w);
                ac[0][0] = __builtin_elementwise_fma(va, w0, ac[0][0]);
                ac[0][1] = __builtin_elementwise_fma(vb, w0, ac[0][1]);
                ac[0][2] = __builtin_elementwise_fma(vc, w0, ac[0][2]);
                ac[0][3] = __builtin_elementwise_fma(vd, w0, ac[0][3]);
                ac[1][0] = __builtin_elementwise_fma(va, w1, ac[1][0]);
                ac[1][1] = __builtin_elementwise_fma(vb, w1, ac[1][1]);
                ac[1][2] = __builtin_elementwise_fma(vc, w1, ac[1][2]);
                ac[1][3] = __builtin_elementwise_fma(vd, w1, ac[1][3]);
                ac[2][0] = __builtin_elementwise_fma(va, w2v, ac[2][0]);
                ac[2][1] = __builtin_elementwise_fma(vb, w2v, ac[2][1]);
                ac[2][2] = __builtin_elementwise_fma(vc, w2v, ac[2][2]);
                ac[2][3] = __builtin_elementwise_fma(vd, w2v, ac[2][3]);
            }
            {
                const f16x2 w0 = u2h(e2.x), w1 = u2h(e2.y), w2v = u2h(e2.z);
                const f16x2 va = u2h(v2.x), vb = u2h(v2.y), vc = u2h(v2.z), vd = u2h(v2.w);
                ac[0][0] = __builtin_elementwise_fma(va, w0, ac[0][0]);
                ac[0][1] = __builtin_elementwise_fma(vb, w0, ac[0][1]);
                ac[0][2] = __builtin_elementwise_fma(vc, w0, ac[0][2]);
                ac[0][3] = __builtin_elementwise_fma(vd, w0, ac[0][3]);
                ac[1][0] = __builtin_elementwise_fma(va, w1, ac[1][0]);
                ac[1][1] = __builtin_elementwise_fma(vb, w1, ac[1][1]);
                ac[1][2] = __builtin_elementwise_fma(vc, w1, ac[1][2]);
                ac[1][3] = __builtin_elementwise_fma(vd, w1, ac[1][3]);
                ac[2][0] = __builtin_elementwise_fma(va, w2v, ac[2][0]);
                ac[2][1] = __builtin_elementwise_fma(vb, w2v, ac[2][1]);
                ac[2][2] = __builtin_elementwise_fma(vc, w2v, ac[2][2]);
                ac[2][3] = __builtin_elementwise_fma(vd, w2v, ac[2][3]);
            }
        }
    }
    #pragma unroll
    for (int o = 0; o < 3; ++o)
        #pragma unroll
        for (int q = 0; q < 4; ++q) {
            ac[o][q] = ac[o][q] + u2h(__shfl_xor((int)h2u(ac[o][q]), 16));
            ac[o][q] = ac[o][q] + u2h(__shfl_xor((int)h2u(ac[o][q]), 32));
        }
    if (lane < 16) {
        __fp16* row = agg + (size_t)node * 384 + fl * 8;
        *(uint4*)(row)       = make_uint4(h2u(ac[0][0]), h2u(ac[0][1]), h2u(ac[0][2]), h2u(ac[0][3]));
        *(uint4*)(row + 128) = make_uint4(h2u(ac[1][0]), h2u(ac[1][1]), h2u(ac[1][2]), h2u(ac[1][3]));
        *(uint4*)(row + 256) = make_uint4(h2u(ac[2][0]), h2u(ac[2][1]), h2u(ac[2][2]), h2u(ac[2][3]));
    }
}

// ============================================================================
// mlp_gemm: y[m,o] = relu(sum_{ki<384} agg[m,ki]*GT[o,ki] + b[o]) + BN stats.
// 64-row M-tile, K-step 64, double-buffered async global_load_lds staging.
// ============================================================================
__global__ __launch_bounds__(256)
void mlp_gemm(const __fp16* __restrict__ agg, const __fp16* __restrict__ GT,
              float* __restrict__ out, int M,
              const float* __restrict__ bias, float* __restrict__ sbuf) {
    __shared__ char smem[49152];
    const int m0 = blockIdx.x * 64;
    const int tid = threadIdx.x;
    const int wave = tid >> 6, lane = tid & 63;
    const int wm0 = wave * 16;
    const int lrow = lane & 15;
    const int kg = lane >> 4;
    const int srow = lane >> 3;
    const int schunk = lane & 7;

    auto STAGE = [&](int buf, int kc) {
        char* base = smem + buf * 24576;
        #pragma unroll
        for (int j = 0; j < 2; ++j) {
            const int rl = wave * 16 + j * 8 + srow;
            const int rg = min(m0 + rl, M - 1);
            gload16(agg + (size_t)rg * 384 + kc * 64 + ((schunk ^ (rl & 7)) << 3),
                    base + (wave * 16 + j * 8) * 128);
        }
        #pragma unroll
        for (int j = 0; j < 4; ++j) {
            const int rl = wave * 32 + j * 8 + srow;
            gload16(GT + (size_t)rl * 384 + kc * 64 + ((schunk ^ (rl & 7)) << 3),
                    base + 8192 + (wave * 32 + j * 8) * 128);
        }
    };

    f32x4 acc[8];
    #pragma unroll
    for (int b = 0; b < 8; ++b) acc[b] = (f32x4){0.f, 0.f, 0.f, 0.f};

    STAGE(0, 0);
    __syncthreads();

    for (int kc = 0; kc < 6; ++kc) {
        const int buf = kc & 1;
        if (kc < 5) STAGE(buf ^ 1, kc + 1);
        const char* Ab = smem + buf * 24576;
        const char* Bb = Ab + 8192;
        f16x8 afr[2];
        #pragma unroll
        for (int ks = 0; ks < 2; ++ks) {
            const int row = wm0 + lrow;
            afr[ks] = *(const f16x8*)(Ab + row * 128 + (((ks * 4 + kg) ^ (row & 7)) << 4));
        }
        #pragma unroll
        for (int nf = 0; nf < 8; ++nf) {
            #pragma unroll
            for (int ks = 0; ks < 2; ++ks) {
                const int row = nf * 16 + lrow;
                f16x8 bfr = *(const f16x8*)(Bb + row * 128 + (((ks * 4 + kg) ^ (row & 7)) << 4));
                acc[nf] = __builtin_amdgcn_mfma_f32_16x16x32_f16(afr[ks], bfr, acc[nf], 0, 0, 0);
            }
        }
        __syncthreads();
    }

    float s[8], s2[8], bv[8];
    #pragma unroll
    for (int nf = 0; nf < 8; ++nf) { s[nf] = 0.f; s2[nf] = 0.f; bv[nf] = bias[nf * 16 + lrow]; }
    #pragma unroll
    for (int nf = 0; nf < 8; ++nf)
        #pragma unroll
        for (int rg = 0; rg < 4; ++rg) {
            const int row = m0 + wm0 + kg * 4 + rg;
            if (row < M) {
                const float v = fmaxf(acc[nf][rg] + bv[nf], 0.f);
                out[(size_t)row * FEAT + nf * 16 + lrow] = v;
                s[nf] += v;
                s2[nf] = fmaf(v, v, s2[nf]);
            }
        }
    #pragma unroll
    for (int nf = 0; nf < 8; ++nf) {
        s[nf]  += __shfl_xor(s[nf], 16);  s[nf]  += __shfl_xor(s[nf], 32);
        s2[nf] += __shfl_xor(s2[nf], 16); s2[nf] += __shfl_xor(s2[nf], 32);
    }
    __syncthreads();
    float* red = (float*)smem;
    if (lane < 16) {
        #pragma unroll
        for (int nf = 0; nf < 8; ++nf) {
            red[wave * 256 + nf * 16 + lane]       = s[nf];
            red[wave * 256 + 128 + nf * 16 + lane] = s2[nf];
        }
    }
    __syncthreads();
    if (tid < 128) {
        const float ss = red[tid] + red[256 + tid] + red[512 + tid] + red[768 + tid];
        const float qq = red[128 + tid] + red[384 + tid] + red[640 + tid] + red[896 + tid];
        float* sb = sbuf + (blockIdx.x & (NSHARD - 1)) * 256;
        atomicAdd(sb + tid, ss);
        atomicAdd(sb + FEAT + tid, qq);
    }
}

// ---- BN normalize (sums the 16 stat shards, derives scale/shift) ----
__global__ void normalize(float* __restrict__ y, const float* __restrict__ sbuf,
                          const float* __restrict__ gamma, const float* __restrict__ beta) {
    __shared__ float sc_s[FEAT], sh_s[FEAT];
    const int t = threadIdx.x;
    if (t < FEAT) {
        float ssum = 0.f, qsum = 0.f;
        #pragma unroll
        for (int sh = 0; sh < NSHARD; ++sh) {
            ssum += sbuf[sh * 256 + t];
            qsum += sbuf[sh * 256 + 128 + t];
        }
        const float mean = ssum / (float)N_NODES;
        const float var  = qsum / (float)N_NODES - mean * mean;
        const float sc   = gamma[t] * rsqrtf(var + BN_EPS);
        sc_s[t] = sc;
        sh_s[t] = beta[t] - mean * sc;
    }
    __syncthreads();
    const int idx = blockIdx.x * blockDim.x + t;
    const int o4 = (idx & 31) * 4;
    float4 v = *(float4*)(y + (size_t)idx * 4);
    const float4 sc = *(const float4*)(sc_s + o4);
    const float4 sh = *(const float4*)(sh_s + o4);
    v.x = fmaf(v.x, sc.x, sh.x);
    v.y = fmaf(v.y, sc.y, sh.y);
    v.z = fmaf(v.z, sc.z, sh.z);
    v.w = fmaf(v.w, sc.w, sh.w);
    *(float4*)(y + (size_t)idx * 4) = v;
}

extern "C" void kernel_launch(void* const* d_in, const int* in_sizes, int n_in,
                              void* d_out, int out_size, void* d_ws, size_t ws_size,
                              hipStream_t stream) {
    const float* feature = (const float*)d_in[0];
    const float* coords  = (const float*)d_in[1];
    const int*   src     = (const int*)d_in[2];
    const int*   dst     = (const int*)d_in[3];
    const int*   order   = (const int*)d_in[4];
    const float* linear  = (const float*)d_in[5];
    const float* attW    = (const float*)d_in[6];
    const float* mlp_w   = (const float*)d_in[7];
    const float* mlp_b   = (const float*)d_in[8];
    const float* gamma   = (const float*)d_in[9];
    const float* beta    = (const float*)d_in[10];
    float* out = (float*)d_out;

    char* p = (char*)d_ws;
    __fp16* fh           = (__fp16*)p;  p += (size_t)N_NODES * FEAT * 2;   // 12.8 MB
    __fp16* agg          = (__fp16*)p;  p += (size_t)N_NODES * 384 * 2;    // 38.4 MB
    __fp16* GT           = (__fp16*)p;  p += (size_t)FEAT * 384 * 2;       // 98 KB
    float4* pk           = (float4*)p;  p += (size_t)N_NODES * 32;         // 1.6 MB
    int4*  edata         = (int4*)p;    p += (size_t)E_EDGES * 16;         // 12.8 MB
    int2*  bbuf          = (int2*)p;    p += (size_t)NBUK * BCAP * 8;      // 8.0 MB
    int*   cnt           = (int*)p;     p += 200064;                       // 50016 ints
    float* sbuf          = (float*)p;   p += NSHARD * 256 * 4;             // 4096 floats
    int*   gcur          = (int*)p;     p += 1024;                         // 256 ints
    int*   rowptr        = (int*)p;     p += 200064;
    int*   cursor        = (int*)p;     p += 200064;
    int*   bsum          = (int*)p;     p += 256;

    const int MB = (N_NODES + 63) / 64;          // 782
    const int AB = (E_EDGES + 2047) / 2048;      // 391

    // zeroing of cnt|sbuf|gcur happens inside g_cast (NZERO ints from cnt)
    g_cast<<<NWB_BLKS + FEAT, 256, 0, stream>>>(feature, coords, attW,
                                                mlp_w, linear, fh, pk, GT, cnt);

    bucketA<<<AB, 256, 0, stream>>>(src, dst, order, cnt, gcur, bbuf);
    scan1<<<NB1, 256, 0, stream>>>(cnt, rowptr, bsum);
    scan3<<<(N_NODES + 255) / 256, 256, 0, stream>>>(rowptr, cursor, bsum);
    bucketB<<<NBUK * NSEG, 256, 0, stream>>>(gcur, bbuf, pk, cursor, edata);

    segagg<<<NWB_BLKS, 256, 0, stream>>>(edata, rowptr, fh, agg);

    mlp_gemm<<<MB, 256, 0, stream>>>(agg, GT, out, N_NODES, mlp_b, sbuf);
    normalize<<<(N_NODES * 32) / 256, 256, 0, stream>>>(out, sbuf, gamma, beta);
}

// Round 20
// 162.572 us; speedup vs baseline: 1.1785x; 1.0586x over previous
//
#include <hip/hip_runtime.h>

#define N_NODES 50000
#define E_EDGES 800000
#define FEAT    128
#define KORD    3
#define BN_EPS  1e-5f
#define NBUK    49          // coarse buckets (dst >> 10)
#define BCAP    20480       // bucket capacity
#define NSHARD  16          // BN-stats atomic shards
#define NSEG    32          // bucketB segments per bucket
#define NWB_BLKS 12500      // (N_NODES*64)/256
#define NZERO   4352        // ints to zero: sbuf(4096) + gcur(256)

typedef __fp16 f16x2 __attribute__((ext_vector_type(2)));
typedef __fp16 f16x8 __attribute__((ext_vector_type(8)));
typedef __attribute__((ext_vector_type(4))) float f32x4;

__device__ __forceinline__ unsigned h2u(f16x2 h) { union { f16x2 h; unsigned u; } c; c.h = h; return c.u; }
__device__ __forceinline__ f16x2 u2h(unsigned u) { union { unsigned u; f16x2 h; } c; c.u = u; return c.h; }

// async global->LDS, 16B per lane (lane lands at ldsbase + lane*16)
__device__ __forceinline__ void gload16(const void* g, void* l) {
    __builtin_amdgcn_global_load_lds(
        (const __attribute__((address_space(1))) unsigned int*)g,
        (__attribute__((address_space(3))) unsigned int*)l, 16, 0, 0);
}

// ---- per node: feature->f16, pack {coords, g=attW@f}; zero sbuf/gcur;
//      tail blocks: fold GT[o][k*128+i] = sum_j L[k][i][j]*W[o][j] ----
__global__ void g_cast(const float* __restrict__ feat,
                       const float* __restrict__ coords,
                       const float* __restrict__ attW,
                       const float* __restrict__ W,
                       const float* __restrict__ L,
                       __fp16* __restrict__ fh,
                       float4* __restrict__ pk,
                       __fp16* __restrict__ GT,
                       int* __restrict__ zbase) {
    __shared__ float wrow[FEAT];
    const int gtid = blockIdx.x * 256 + threadIdx.x;
    if (gtid < NZERO) zbase[gtid] = 0;       // sbuf + gcur zeroing
    if (blockIdx.x >= NWB_BLKS) {            // gprep tail blocks (128)
        const int o = blockIdx.x - NWB_BLKS;
        const int i = threadIdx.x;
        if (i < FEAT) wrow[i] = W[o * FEAT + i];
        __syncthreads();
        if (i < FEAT) {
            #pragma unroll
            for (int k = 0; k < KORD; ++k) {
                const float* lp = L + ((size_t)k * FEAT + i) * FEAT;
                float acc = 0.f;
                #pragma unroll 8
                for (int j = 0; j < FEAT; ++j) acc = fmaf(lp[j], wrow[j], acc);
                GT[(size_t)o * 384 + k * FEAT + i] = (__fp16)acc;
            }
        }
        return;
    }
    const int node = gtid >> 6;
    const int lane = threadIdx.x & 63;
    if (node >= N_NODES) return;
    const float2 f = *(const float2*)(feat + (size_t)node * FEAT + lane * 2);
    *(f16x2*)(fh + (size_t)node * FEAT + lane * 2) = __builtin_amdgcn_cvt_pkrtz(f.x, f.y);
    float gg[3];
    #pragma unroll
    for (int j = 0; j < 3; ++j) {
        float p = f.x * attW[j * FEAT + lane * 2] + f.y * attW[j * FEAT + lane * 2 + 1];
        #pragma unroll
        for (int off = 32; off; off >>= 1) p += __shfl_xor(p, off);
        gg[j] = p;
    }
    if (lane == 0) {
        const float c0 = coords[node * 3 + 0], c1 = coords[node * 3 + 1], c2 = coords[node * 3 + 2];
        pk[2 * node]     = make_float4(c0, c1, c2, gg[0]);
        pk[2 * node + 1] = make_float4(gg[1], gg[2], 0.f, 0.f);
    }
}

// ============ CSR build ============
// bucketA: rank edges into 49 coarse buckets (NO global histogram atomics)
__global__ __launch_bounds__(256)
void bucketA(const int* __restrict__ src, const int* __restrict__ dst,
             const int* __restrict__ order,
             int* __restrict__ gcur, int2* __restrict__ bbuf) {
    __shared__ int lcnt[4][NBUK];
    __shared__ int wbase[4][NBUK];
    const int tid = threadIdx.x;
    const int wid = tid >> 6;
    if (tid < NBUK) {
        lcnt[0][tid] = 0; lcnt[1][tid] = 0; lcnt[2][tid] = 0; lcnt[3][tid] = 0;
    }
    __syncthreads();
    const int e0 = blockIdx.x * 2048;
    int b[8], r[8], so[8], dd[8];
    #pragma unroll
    for (int i = 0; i < 8; ++i) {
        const int e = e0 + i * 256 + tid;
        if (e < E_EDGES) {
            dd[i] = dst[e];
            so[i] = (order[e] << 16) | src[e];
            b[i] = dd[i] >> 10;
            r[i] = atomicAdd(&lcnt[wid][b[i]], 1);
        } else b[i] = -1;
    }
    __syncthreads();
    if (tid < NBUK) {
        const int w0 = lcnt[0][tid], w1 = lcnt[1][tid], w2 = lcnt[2][tid], w3 = lcnt[3][tid];
        const int base = atomicAdd(gcur + tid, w0 + w1 + w2 + w3);
        wbase[0][tid] = base;
        wbase[1][tid] = base + w0;
        wbase[2][tid] = base + w0 + w1;
        wbase[3][tid] = base + w0 + w1 + w2;
    }
    __syncthreads();
    #pragma unroll
    for (int i = 0; i < 8; ++i)
        if (b[i] >= 0)
            bbuf[(size_t)b[i] * BCAP + wbase[wid][b[i]] + r[i]] = make_int2(so[i], dd[i]);
}

// ---- hist2: per-bucket LDS histogram (dst window = 1024 nodes) + local scan
//      + cross-bucket prefix (wave-scan of gcur) -> rowptr & cursor.
//      Replaces global cnt histogram + scan1 + scan3.
__global__ __launch_bounds__(256)
void hist2(const int* __restrict__ gcur, const int2* __restrict__ bbuf,
           int* __restrict__ rowptr, int* __restrict__ cursor) {
    __shared__ int lhist[1024];
    __shared__ int lscan[256];
    __shared__ int boff_s;
    const int b = blockIdx.x;
    const int t = threadIdx.x;
    #pragma unroll
    for (int i = 0; i < 4; ++i) lhist[t + i * 256] = 0;
    __syncthreads();
    const int n = gcur[b];
    const int base = b << 10;
    for (int i = t; i < n; i += 256)
        atomicAdd(&lhist[bbuf[(size_t)b * BCAP + i].y - base], 1);
    __syncthreads();
    if (t < 64) {   // cross-bucket exclusive prefix of gcur at position b
        const int v = (t < NBUK) ? gcur[t] : 0;
        int incl = v;
        #pragma unroll
        for (int off = 1; off < 64; off <<= 1) {
            const int u = __shfl_up(incl, off);
            if (t >= off) incl += u;
        }
        if (t == b) boff_s = incl - v;
    }
    int v[4];
    #pragma unroll
    for (int i = 0; i < 4; ++i) v[i] = lhist[t * 4 + i];
    lscan[t] = v[0] + v[1] + v[2] + v[3];
    __syncthreads();
    for (int off = 1; off < 256; off <<= 1) {
        const int u = (t >= off) ? lscan[t - off] : 0;
        __syncthreads();
        lscan[t] += u;
        __syncthreads();
    }
    int excl = (t ? lscan[t - 1] : 0) + boff_s;
    #pragma unroll
    for (int i = 0; i < 4; ++i) {
        const int node = base + t * 4 + i;
        if (node < N_NODES) { rowptr[node] = excl; cursor[node] = excl; }
        excl += v[i];
    }
    if (b == 0 && t == 0) rowptr[N_NODES] = E_EDGES;
}

// ---- bucketB: CSR scatter + per-edge att/invdist, ONE packed 16B store ----
__global__ void bucketB(const int* __restrict__ gcur, const int2* __restrict__ bbuf,
                        const float4* __restrict__ pk,
                        int* __restrict__ cursor, int4* __restrict__ edata) {
    const int b = blockIdx.x / NSEG;
    const int seg = blockIdx.x % NSEG;
    const int n = gcur[b];
    const int lo = (int)((long)n * seg / NSEG), hi = (int)((long)n * (seg + 1) / NSEG);
    for (int i = lo + (int)threadIdx.x; i < hi; i += 256) {
        const int2 ent = bbuf[(size_t)b * BCAP + i];
        const int s = ent.x & 0xFFFF;
        const int d = ent.y;
        const float4 a0 = pk[2 * s], a1 = pk[2 * s + 1], c0 = pk[2 * d];
        const float dx = a0.x - c0.x, dy = a0.y - c0.y, dz = a0.z - c0.z;
        const float att  = dx * a0.w + dy * a1.x + dz * a1.y;
        const float invd = 1.f / (dx * dx + dy * dy + dz * dz + 1.f);
        const int pos = atomicAdd(cursor + d, 1);
        edata[pos] = make_int4(ent.x, __float_as_int(att), __float_as_int(invd), 0);
    }
}

// ---- segment softmax + per-order gather-aggregate (stream + fh gather) ----
__global__ void segagg(const int4* __restrict__ edata,
                       const int* __restrict__ rowptr,
                       const __fp16* __restrict__ fh,
                       __fp16* __restrict__ agg) {
    __shared__ uint4 stash[4][64];
    const int node = (blockIdx.x * blockDim.x + threadIdx.x) >> 6;
    const int lane = threadIdx.x & 63;
    const int wid  = threadIdx.x >> 6;
    if (node >= N_NODES) return;
    const int beg = rowptr[node], end = rowptr[node + 1];

    // phase 1: online (m,s) over contiguous edata; cache chunk-0 record
    int4 e0c = make_int4(0, 0xFF800000, 0, 0);   // att = -inf
    float m = -1e30f, s = 0.f;
    int nch = 0;
    for (int cb = beg; cb < end; cb += 64, ++nch) {
        const int p = cb + lane;
        float a = -1e30f;
        if (p < end) {
            const int4 e = edata[p];
            a = __int_as_float(e.y);
            if (nch == 0) e0c = e;
        }
        const float mn = fmaxf(m, a);
        s = s * __expf(m - mn) + ((p < end) ? __expf(a - mn) : 0.f);
        m = mn;
    }
    #pragma unroll
    for (int off = 32; off; off >>= 1) {
        const float mo = __shfl_xor(m, off), so_ = __shfl_xor(s, off);
        const float mn = fmaxf(m, mo);
        s = s * __expf(m - mn) + so_ * __expf(mo - mn);
        m = mn;
    }
    const float inv_s = s > 0.f ? 1.f / s : 0.f;

    // phase 2: 4-edge groups, 2 gathers in flight
    const int grp = lane >> 4;
    const int fl  = lane & 15;
    f16x2 ac[3][4];
    #pragma unroll
    for (int o = 0; o < 3; ++o)
        #pragma unroll
        for (int q = 0; q < 4; ++q) ac[o][q] = (f16x2){0, 0};

    int ch = 0;
    for (int cb = beg; cb < end; cb += 64, ++ch) {
        const int p = cb + lane;
        float wl = 0.f; int so = 0;
        if (p < end) {
            const int4 e = (ch == 0) ? e0c : edata[p];
            wl = __expf(__int_as_float(e.y) - m) * inv_s * __int_as_float(e.z);
            so = e.x;
        }
        const int k = so >> 16;
        const __fp16 wh = (__fp16)wl;
        f16x2 w2; w2.x = wh; w2.y = wh;
        const unsigned uw = h2u(w2);
        stash[wid][lane] = make_uint4(k == 0 ? uw : 0u, k == 1 ? uw : 0u,
                                      k == 2 ? uw : 0u, (unsigned)(so & 0xFFFF));
        const int ne = min(64, end - cb);
        const uint4* st = stash[wid];
        for (int t = 0; t < ne; t += 8) {
            const uint4 e1 = st[t + grp];
            const uint4 e2 = st[t + 4 + grp];
            const uint4 v1 = *(const uint4*)(fh + ((size_t)e1.w << 7) + fl * 8);
            const uint4 v2 = *(const uint4*)(fh + ((size_t)e2.w << 7) + fl * 8);
            {
                const f16x2 w0 = u2h(e1.x), w1 = u2h(e1.y), w2v = u2h(e1.z);
                const f16x2 va = u2h(v1.x), vb = u2h(v1.y), vc = u2h(v1.z), vd = u2h(v1.w);
                ac[0][0] = __builtin_elementwise_fma(va, w0, ac[0][0]);
                ac[0][1] = __builtin_elementwise_fma(vb, w0, ac[0][1]);
                ac[0][2] = __builtin_elementwise_fma(vc, w0, ac[0][2]);
                ac[0][3] = __builtin_elementwise_fma(vd, w0, ac[0][3]);
                ac[1][0] = __builtin_elementwise_fma(va, w1, ac[1][0]);
                ac[1][1] = __builtin_elementwise_fma(vb, w1, ac[1][1]);
                ac[1][2] = __builtin_elementwise_fma(vc, w1, ac[1][2]);
                ac[1][3] = __builtin_elementwise_fma(vd, w1, ac[1][3]);
                ac[2][0] = __builtin_elementwise_fma(va, w2v, ac[2][0]);
                ac[2][1] = __builtin_elementwise_fma(vb, w2v, ac[2][1]);
                ac[2][2] = __builtin_elementwise_fma(vc, w2v, ac[2][2]);
                ac[2][3] = __builtin_elementwise_fma(vd, w2v, ac[2][3]);
            }
            {
                const f16x2 w0 = u2h(e2.x), w1 = u2h(e2.y), w2v = u2h(e2.z);
                const f16x2 va = u2h(v2.x), vb = u2h(v2.y), vc = u2h(v2.z), vd = u2h(v2.w);
                ac[0][0] = __builtin_elementwise_fma(va, w0, ac[0][0]);
                ac[0][1] = __builtin_elementwise_fma(vb, w0, ac[0][1]);
                ac[0][2] = __builtin_elementwise_fma(vc, w0, ac[0][2]);
                ac[0][3] = __builtin_elementwise_fma(vd, w0, ac[0][3]);
                ac[1][0] = __builtin_elementwise_fma(va, w1, ac[1][0]);
                ac[1][1] = __builtin_elementwise_fma(vb, w1, ac[1][1]);
                ac[1][2] = __builtin_elementwise_fma(vc, w1, ac[1][2]);
                ac[1][3] = __builtin_elementwise_fma(vd, w1, ac[1][3]);
                ac[2][0] = __builtin_elementwise_fma(va, w2v, ac[2][0]);
                ac[2][1] = __builtin_elementwise_fma(vb, w2v, ac[2][1]);
                ac[2][2] = __builtin_elementwise_fma(vc, w2v, ac[2][2]);
                ac[2][3] = __builtin_elementwise_fma(vd, w2v, ac[2][3]);
            }
        }
    }
    #pragma unroll
    for (int o = 0; o < 3; ++o)
        #pragma unroll
        for (int q = 0; q < 4; ++q) {
            ac[o][q] = ac[o][q] + u2h(__shfl_xor((int)h2u(ac[o][q]), 16));
            ac[o][q] = ac[o][q] + u2h(__shfl_xor((int)h2u(ac[o][q]), 32));
        }
    if (lane < 16) {
        __fp16* row = agg + (size_t)node * 384 + fl * 8;
        *(uint4*)(row)       = make_uint4(h2u(ac[0][0]), h2u(ac[0][1]), h2u(ac[0][2]), h2u(ac[0][3]));
        *(uint4*)(row + 128) = make_uint4(h2u(ac[1][0]), h2u(ac[1][1]), h2u(ac[1][2]), h2u(ac[1][3]));
        *(uint4*)(row + 256) = make_uint4(h2u(ac[2][0]), h2u(ac[2][1]), h2u(ac[2][2]), h2u(ac[2][3]));
    }
}

// ============================================================================
// mlp_gemm: y[m,o] = relu(sum_{ki<384} agg[m,ki]*GT[o,ki] + b[o]) + BN stats.
// 64-row M-tile, K-step 64, double-buffered async global_load_lds staging.
// ============================================================================
__global__ __launch_bounds__(256)
void mlp_gemm(const __fp16* __restrict__ agg, const __fp16* __restrict__ GT,
              float* __restrict__ out, int M,
              const float* __restrict__ bias, float* __restrict__ sbuf) {
    __shared__ char smem[49152];
    const int m0 = blockIdx.x * 64;
    const int tid = threadIdx.x;
    const int wave = tid >> 6, lane = tid & 63;
    const int wm0 = wave * 16;
    const int lrow = lane & 15;
    const int kg = lane >> 4;
    const int srow = lane >> 3;
    const int schunk = lane & 7;

    auto STAGE = [&](int buf, int kc) {
        char* base = smem + buf * 24576;
        #pragma unroll
        for (int j = 0; j < 2; ++j) {
            const int rl = wave * 16 + j * 8 + srow;
            const int rg = min(m0 + rl, M - 1);
            gload16(agg + (size_t)rg * 384 + kc * 64 + ((schunk ^ (rl & 7)) << 3),
                    base + (wave * 16 + j * 8) * 128);
        }
        #pragma unroll
        for (int j = 0; j < 4; ++j) {
            const int rl = wave * 32 + j * 8 + srow;
            gload16(GT + (size_t)rl * 384 + kc * 64 + ((schunk ^ (rl & 7)) << 3),
                    base + 8192 + (wave * 32 + j * 8) * 128);
        }
    };

    f32x4 acc[8];
    #pragma unroll
    for (int b = 0; b < 8; ++b) acc[b] = (f32x4){0.f, 0.f, 0.f, 0.f};

    STAGE(0, 0);
    __syncthreads();

    for (int kc = 0; kc < 6; ++kc) {
        const int buf = kc & 1;
        if (kc < 5) STAGE(buf ^ 1, kc + 1);
        const char* Ab = smem + buf * 24576;
        const char* Bb = Ab + 8192;
        f16x8 afr[2];
        #pragma unroll
        for (int ks = 0; ks < 2; ++ks) {
            const int row = wm0 + lrow;
            afr[ks] = *(const f16x8*)(Ab + row * 128 + (((ks * 4 + kg) ^ (row & 7)) << 4));
        }
        #pragma unroll
        for (int nf = 0; nf < 8; ++nf) {
            #pragma unroll
            for (int ks = 0; ks < 2; ++ks) {
                const int row = nf * 16 + lrow;
                f16x8 bfr = *(const f16x8*)(Bb + row * 128 + (((ks * 4 + kg) ^ (row & 7)) << 4));
                acc[nf] = __builtin_amdgcn_mfma_f32_16x16x32_f16(afr[ks], bfr, acc[nf], 0, 0, 0);
            }
        }
        __syncthreads();
    }

    float s[8], s2[8], bv[8];
    #pragma unroll
    for (int nf = 0; nf < 8; ++nf) { s[nf] = 0.f; s2[nf] = 0.f; bv[nf] = bias[nf * 16 + lrow]; }
    #pragma unroll
    for (int nf = 0; nf < 8; ++nf)
        #pragma unroll
        for (int rg = 0; rg < 4; ++rg) {
            const int row = m0 + wm0 + kg * 4 + rg;
            if (row < M) {
                const float v = fmaxf(acc[nf][rg] + bv[nf], 0.f);
                out[(size_t)row * FEAT + nf * 16 + lrow] = v;
                s[nf] += v;
                s2[nf] = fmaf(v, v, s2[nf]);
            }
        }
    #pragma unroll
    for (int nf = 0; nf < 8; ++nf) {
        s[nf]  += __shfl_xor(s[nf], 16);  s[nf]  += __shfl_xor(s[nf], 32);
        s2[nf] += __shfl_xor(s2[nf], 16); s2[nf] += __shfl_xor(s2[nf], 32);
    }
    __syncthreads();
    float* red = (float*)smem;
    if (lane < 16) {
        #pragma unroll
        for (int nf = 0; nf < 8; ++nf) {
            red[wave * 256 + nf * 16 + lane]       = s[nf];
            red[wave * 256 + 128 + nf * 16 + lane] = s2[nf];
        }
    }
    __syncthreads();
    if (tid < 128) {
        const float ss = red[tid] + red[256 + tid] + red[512 + tid] + red[768 + tid];
        const float qq = red[128 + tid] + red[384 + tid] + red[640 + tid] + red[896 + tid];
        float* sb = sbuf + (blockIdx.x & (NSHARD - 1)) * 256;
        atomicAdd(sb + tid, ss);
        atomicAdd(sb + FEAT + tid, qq);
    }
}

// ---- BN normalize (sums the 16 stat shards, derives scale/shift) ----
__global__ void normalize(float* __restrict__ y, const float* __restrict__ sbuf,
                          const float* __restrict__ gamma, const float* __restrict__ beta) {
    __shared__ float sc_s[FEAT], sh_s[FEAT];
    const int t = threadIdx.x;
    if (t < FEAT) {
        float ssum = 0.f, qsum = 0.f;
        #pragma unroll
        for (int sh = 0; sh < NSHARD; ++sh) {
            ssum += sbuf[sh * 256 + t];
            qsum += sbuf[sh * 256 + 128 + t];
        }
        const float mean = ssum / (float)N_NODES;
        const float var  = qsum / (float)N_NODES - mean * mean;
        const float sc   = gamma[t] * rsqrtf(var + BN_EPS);
        sc_s[t] = sc;
        sh_s[t] = beta[t] - mean * sc;
    }
    __syncthreads();
    const int idx = blockIdx.x * blockDim.x + t;
    const int o4 = (idx & 31) * 4;
    float4 v = *(float4*)(y + (size_t)idx * 4);
    const float4 sc = *(const float4*)(sc_s + o4);
    const float4 sh = *(const float4*)(sh_s + o4);
    v.x = fmaf(v.x, sc.x, sh.x);
    v.y = fmaf(v.y, sc.y, sh.y);
    v.z = fmaf(v.z, sc.z, sh.z);
    v.w = fmaf(v.w, sc.w, sh.w);
    *(float4*)(y + (size_t)idx * 4) = v;
}

extern "C" void kernel_launch(void* const* d_in, const int* in_sizes, int n_in,
                              void* d_out, int out_size, void* d_ws, size_t ws_size,
                              hipStream_t stream) {
    const float* feature = (const float*)d_in[0];
    const float* coords  = (const float*)d_in[1];
    const int*   src     = (const int*)d_in[2];
    const int*   dst     = (const int*)d_in[3];
    const int*   order   = (const int*)d_in[4];
    const float* linear  = (const float*)d_in[5];
    const float* attW    = (const float*)d_in[6];
    const float* mlp_w   = (const float*)d_in[7];
    const float* mlp_b   = (const float*)d_in[8];
    const float* gamma   = (const float*)d_in[9];
    const float* beta    = (const float*)d_in[10];
    float* out = (float*)d_out;

    char* p = (char*)d_ws;
    __fp16* fh           = (__fp16*)p;  p += (size_t)N_NODES * FEAT * 2;   // 12.8 MB
    __fp16* agg          = (__fp16*)p;  p += (size_t)N_NODES * 384 * 2;    // 38.4 MB
    __fp16* GT           = (__fp16*)p;  p += (size_t)FEAT * 384 * 2;       // 98 KB
    float4* pk           = (float4*)p;  p += (size_t)N_NODES * 32;         // 1.6 MB
    int4*  edata         = (int4*)p;    p += (size_t)E_EDGES * 16;         // 12.8 MB
    int2*  bbuf          = (int2*)p;    p += (size_t)NBUK * BCAP * 8;      // 8.0 MB
    float* sbuf          = (float*)p;   p += NSHARD * 256 * 4;             // 4096 floats
    int*   gcur          = (int*)p;     p += 1024;                         // 256 ints
    int*   rowptr        = (int*)p;     p += 200064;
    int*   cursor        = (int*)p;     p += 200064;

    const int MB = (N_NODES + 63) / 64;          // 782
    const int AB = (E_EDGES + 2047) / 2048;      // 391

    // zeroing of sbuf|gcur happens inside g_cast (NZERO ints from sbuf)
    g_cast<<<NWB_BLKS + FEAT, 256, 0, stream>>>(feature, coords, attW,
                                                mlp_w, linear, fh, pk, GT, (int*)sbuf);

    bucketA<<<AB, 256, 0, stream>>>(src, dst, order, gcur, bbuf);
    hist2<<<NBUK, 256, 0, stream>>>(gcur, bbuf, rowptr, cursor);
    bucketB<<<NBUK * NSEG, 256, 0, stream>>>(gcur, bbuf, pk, cursor, edata);

    segagg<<<NWB_BLKS, 256, 0, stream>>>(edata, rowptr, fh, agg);

    mlp_gemm<<<MB, 256, 0, stream>>>(agg, GT, out, N_NODES, mlp_b, sbuf);
    normalize<<<(N_NODES * 32) / 256, 256, 0, stream>>>(out, sbuf, gamma, beta);
}

// Round 21
// 152.898 us; speedup vs baseline: 1.2531x; 1.0633x over previous
//
#include <hip/hip_runtime.h>

#define N_NODES 50000
#define E_EDGES 800000
#define FEAT    128
#define KORD    3
#define BN_EPS  1e-5f
#define NBUK    49          // coarse buckets (dst >> 10)
#define BCAP    20480       // bucket capacity
#define NSHARD  16          // BN-stats atomic shards
#define NSEG    32          // bucketB segments per bucket
#define NGC_BLKS 3125       // g_cast main blocks: 16 nodes/block (4 nodes/wave)
#define NWB_BLKS 12500      // segagg blocks (1 node/wave)
#define NZERO   4352        // ints to zero: sbuf(4096) + gcur(256)

typedef __fp16 f16x2 __attribute__((ext_vector_type(2)));
typedef __fp16 f16x8 __attribute__((ext_vector_type(8)));
typedef __attribute__((ext_vector_type(4))) float f32x4;

__device__ __forceinline__ unsigned h2u(f16x2 h) { union { f16x2 h; unsigned u; } c; c.h = h; return c.u; }
__device__ __forceinline__ f16x2 u2h(unsigned u) { union { unsigned u; f16x2 h; } c; c.u = u; return c.h; }

// async global->LDS, 16B per lane (lane lands at ldsbase + lane*16)
__device__ __forceinline__ void gload16(const void* g, void* l) {
    __builtin_amdgcn_global_load_lds(
        (const __attribute__((address_space(1))) unsigned int*)g,
        (__attribute__((address_space(3))) unsigned int*)l, 16, 0, 0);
}

// ---- per node: feature->f16, pack {coords, g=attW@f}; zero sbuf/gcur;
//      4 nodes/wave (16 lanes x 8 feats each, 12-shfl reduce);
//      tail blocks: fold GT[o][k*128+i] = sum_j L[k][i][j]*W[o][j] ----
__global__ void g_cast(const float* __restrict__ feat,
                       const float* __restrict__ coords,
                       const float* __restrict__ attW,
                       const float* __restrict__ W,
                       const float* __restrict__ L,
                       __fp16* __restrict__ fh,
                       float4* __restrict__ pk,
                       __fp16* __restrict__ GT,
                       int* __restrict__ zbase) {
    __shared__ float wrow[FEAT];
    const int gtid = blockIdx.x * 256 + threadIdx.x;
    if (gtid < NZERO) zbase[gtid] = 0;       // sbuf + gcur zeroing
    if (blockIdx.x >= NGC_BLKS) {            // gprep tail blocks (128)
        const int o = blockIdx.x - NGC_BLKS;
        const int i = threadIdx.x;
        if (i < FEAT) wrow[i] = W[o * FEAT + i];
        __syncthreads();
        if (i < FEAT) {
            #pragma unroll
            for (int k = 0; k < KORD; ++k) {
                const float* lp = L + ((size_t)k * FEAT + i) * FEAT;
                float acc = 0.f;
                #pragma unroll 8
                for (int j = 0; j < FEAT; ++j) acc = fmaf(lp[j], wrow[j], acc);
                GT[(size_t)o * 384 + k * FEAT + i] = (__fp16)acc;
            }
        }
        return;
    }
    // 16 nodes per block: node = blk*16 + (tid>>4); lane sub = feature slice
    const int node = blockIdx.x * 16 + (threadIdx.x >> 4);
    const int sub  = threadIdx.x & 15;       // 8-feature slice
    const float4 fa = *(const float4*)(feat + (size_t)node * FEAT + sub * 8);
    const float4 fb = *(const float4*)(feat + (size_t)node * FEAT + sub * 8 + 4);
    // fh: 8 f32 -> 4x f16x2, one uint4 store (contiguous 256B per node)
    uint4 ov;
    ov.x = h2u(__builtin_amdgcn_cvt_pkrtz(fa.x, fa.y));
    ov.y = h2u(__builtin_amdgcn_cvt_pkrtz(fa.z, fa.w));
    ov.z = h2u(__builtin_amdgcn_cvt_pkrtz(fb.x, fb.y));
    ov.w = h2u(__builtin_amdgcn_cvt_pkrtz(fb.z, fb.w));
    *(uint4*)(fh + (size_t)node * FEAT + sub * 8) = ov;
    // 3 dot products over this lane's 8 features
    float g0, g1, g2;
    {
        const float4 wa0 = *(const float4*)(attW + 0 * FEAT + sub * 8);
        const float4 wb0 = *(const float4*)(attW + 0 * FEAT + sub * 8 + 4);
        const float4 wa1 = *(const float4*)(attW + 1 * FEAT + sub * 8);
        const float4 wb1 = *(const float4*)(attW + 1 * FEAT + sub * 8 + 4);
        const float4 wa2 = *(const float4*)(attW + 2 * FEAT + sub * 8);
        const float4 wb2 = *(const float4*)(attW + 2 * FEAT + sub * 8 + 4);
        g0 = fa.x*wa0.x + fa.y*wa0.y + fa.z*wa0.z + fa.w*wa0.w
           + fb.x*wb0.x + fb.y*wb0.y + fb.z*wb0.z + fb.w*wb0.w;
        g1 = fa.x*wa1.x + fa.y*wa1.y + fa.z*wa1.z + fa.w*wa1.w
           + fb.x*wb1.x + fb.y*wb1.y + fb.z*wb1.z + fb.w*wb1.w;
        g2 = fa.x*wa2.x + fa.y*wa2.y + fa.z*wa2.z + fa.w*wa2.w
           + fb.x*wb2.x + fb.y*wb2.y + fb.z*wb2.z + fb.w*wb2.w;
    }
    #pragma unroll
    for (int off = 8; off; off >>= 1) {      // reduce within 16-lane group
        g0 += __shfl_xor(g0, off);
        g1 += __shfl_xor(g1, off);
        g2 += __shfl_xor(g2, off);
    }
    if (sub == 0) {
        const float c0 = coords[node * 3 + 0], c1 = coords[node * 3 + 1], c2 = coords[node * 3 + 2];
        pk[2 * node]     = make_float4(c0, c1, c2, g0);
        pk[2 * node + 1] = make_float4(g1, g2, 0.f, 0.f);
    }
}

// ============ CSR build ============
// bucketA: rank edges into 49 coarse buckets (NO global histogram atomics)
__global__ __launch_bounds__(256)
void bucketA(const int* __restrict__ src, const int* __restrict__ dst,
             const int* __restrict__ order,
             int* __restrict__ gcur, int2* __restrict__ bbuf) {
    __shared__ int lcnt[4][NBUK];
    __shared__ int wbase[4][NBUK];
    const int tid = threadIdx.x;
    const int wid = tid >> 6;
    if (tid < NBUK) {
        lcnt[0][tid] = 0; lcnt[1][tid] = 0; lcnt[2][tid] = 0; lcnt[3][tid] = 0;
    }
    __syncthreads();
    const int e0 = blockIdx.x * 2048;
    int b[8], r[8], so[8], dd[8];
    #pragma unroll
    for (int i = 0; i < 8; ++i) {
        const int e = e0 + i * 256 + tid;
        if (e < E_EDGES) {
            dd[i] = dst[e];
            so[i] = (order[e] << 16) | src[e];
            b[i] = dd[i] >> 10;
            r[i] = atomicAdd(&lcnt[wid][b[i]], 1);
        } else b[i] = -1;
    }
    __syncthreads();
    if (tid < NBUK) {
        const int w0 = lcnt[0][tid], w1 = lcnt[1][tid], w2 = lcnt[2][tid], w3 = lcnt[3][tid];
        const int base = atomicAdd(gcur + tid, w0 + w1 + w2 + w3);
        wbase[0][tid] = base;
        wbase[1][tid] = base + w0;
        wbase[2][tid] = base + w0 + w1;
        wbase[3][tid] = base + w0 + w1 + w2;
    }
    __syncthreads();
    #pragma unroll
    for (int i = 0; i < 8; ++i)
        if (b[i] >= 0)
            bbuf[(size_t)b[i] * BCAP + wbase[wid][b[i]] + r[i]] = make_int2(so[i], dd[i]);
}

// ---- hist2: per-bucket LDS histogram + local scan + cross-bucket prefix ----
__global__ __launch_bounds__(256)
void hist2(const int* __restrict__ gcur, const int2* __restrict__ bbuf,
           int* __restrict__ rowptr, int* __restrict__ cursor) {
    __shared__ int lhist[1024];
    __shared__ int lscan[256];
    __shared__ int boff_s;
    const int b = blockIdx.x;
    const int t = threadIdx.x;
    #pragma unroll
    for (int i = 0; i < 4; ++i) lhist[t + i * 256] = 0;
    __syncthreads();
    const int n = gcur[b];
    const int base = b << 10;
    for (int i = t; i < n; i += 256)
        atomicAdd(&lhist[bbuf[(size_t)b * BCAP + i].y - base], 1);
    __syncthreads();
    if (t < 64) {   // cross-bucket exclusive prefix of gcur at position b
        const int v = (t < NBUK) ? gcur[t] : 0;
        int incl = v;
        #pragma unroll
        for (int off = 1; off < 64; off <<= 1) {
            const int u = __shfl_up(incl, off);
            if (t >= off) incl += u;
        }
        if (t == b) boff_s = incl - v;
    }
    int v[4];
    #pragma unroll
    for (int i = 0; i < 4; ++i) v[i] = lhist[t * 4 + i];
    lscan[t] = v[0] + v[1] + v[2] + v[3];
    __syncthreads();
    for (int off = 1; off < 256; off <<= 1) {
        const int u = (t >= off) ? lscan[t - off] : 0;
        __syncthreads();
        lscan[t] += u;
        __syncthreads();
    }
    int excl = (t ? lscan[t - 1] : 0) + boff_s;
    #pragma unroll
    for (int i = 0; i < 4; ++i) {
        const int node = base + t * 4 + i;
        if (node < N_NODES) { rowptr[node] = excl; cursor[node] = excl; }
        excl += v[i];
    }
    if (b == 0 && t == 0) rowptr[N_NODES] = E_EDGES;
}

// ---- bucketB: CSR scatter + per-edge att/invdist, ONE packed 16B store ----
__global__ void bucketB(const int* __restrict__ gcur, const int2* __restrict__ bbuf,
                        const float4* __restrict__ pk,
                        int* __restrict__ cursor, int4* __restrict__ edata) {
    const int b = blockIdx.x / NSEG;
    const int seg = blockIdx.x % NSEG;
    const int n = gcur[b];
    const int lo = (int)((long)n * seg / NSEG), hi = (int)((long)n * (seg + 1) / NSEG);
    for (int i = lo + (int)threadIdx.x; i < hi; i += 256) {
        const int2 ent = bbuf[(size_t)b * BCAP + i];
        const int s = ent.x & 0xFFFF;
        const int d = ent.y;
        const float4 a0 = pk[2 * s], a1 = pk[2 * s + 1], c0 = pk[2 * d];
        const float dx = a0.x - c0.x, dy = a0.y - c0.y, dz = a0.z - c0.z;
        const float att  = dx * a0.w + dy * a1.x + dz * a1.y;
        const float invd = 1.f / (dx * dx + dy * dy + dz * dz + 1.f);
        const int pos = atomicAdd(cursor + d, 1);
        edata[pos] = make_int4(ent.x, __float_as_int(att), __float_as_int(invd), 0);
    }
}

// ---- segment softmax + per-order gather-aggregate (stream + fh gather) ----
__global__ void segagg(const int4* __restrict__ edata,
                       const int* __restrict__ rowptr,
                       const __fp16* __restrict__ fh,
                       __fp16* __restrict__ agg) {
    __shared__ uint4 stash[4][64];
    const int node = (blockIdx.x * blockDim.x + threadIdx.x) >> 6;
    const int lane = threadIdx.x & 63;
    const int wid  = threadIdx.x >> 6;
    if (node >= N_NODES) return;
    const int beg = rowptr[node], end = rowptr[node + 1];

    // phase 1: online (m,s) over contiguous edata; cache chunk-0 record
    int4 e0c = make_int4(0, 0xFF800000, 0, 0);   // att = -inf
    float m = -1e30f, s = 0.f;
    int nch = 0;
    for (int cb = beg; cb < end; cb += 64, ++nch) {
        const int p = cb + lane;
        float a = -1e30f;
        if (p < end) {
            const int4 e = edata[p];
            a = __int_as_float(e.y);
            if (nch == 0) e0c = e;
        }
        const float mn = fmaxf(m, a);
        s = s * __expf(m - mn) + ((p < end) ? __expf(a - mn) : 0.f);
        m = mn;
    }
    #pragma unroll
    for (int off = 32; off; off >>= 1) {
        const float mo = __shfl_xor(m, off), so_ = __shfl_xor(s, off);
        const float mn = fmaxf(m, mo);
        s = s * __expf(m - mn) + so_ * __expf(mo - mn);
        m = mn;
    }
    const float inv_s = s > 0.f ? 1.f / s : 0.f;

    // phase 2: 4-edge groups, 2 gathers in flight
    const int grp = lane >> 4;
    const int fl  = lane & 15;
    f16x2 ac[3][4];
    #pragma unroll
    for (int o = 0; o < 3; ++o)
        #pragma unroll
        for (int q = 0; q < 4; ++q) ac[o][q] = (f16x2){0, 0};

    int ch = 0;
    for (int cb = beg; cb < end; cb += 64, ++ch) {
        const int p = cb + lane;
        float wl = 0.f; int so = 0;
        if (p < end) {
            const int4 e = (ch == 0) ? e0c : edata[p];
            wl = __expf(__int_as_float(e.y) - m) * inv_s * __int_as_float(e.z);
            so = e.x;
        }
        const int k = so >> 16;
        const __fp16 wh = (__fp16)wl;
        f16x2 w2; w2.x = wh; w2.y = wh;
        const unsigned uw = h2u(w2);
        stash[wid][lane] = make_uint4(k == 0 ? uw : 0u, k == 1 ? uw : 0u,
                                      k == 2 ? uw : 0u, (unsigned)(so & 0xFFFF));
        const int ne = min(64, end - cb);
        const uint4* st = stash[wid];
        for (int t = 0; t < ne; t += 8) {
            const uint4 e1 = st[t + grp];
            const uint4 e2 = st[t + 4 + grp];
            const uint4 v1 = *(const uint4*)(fh + ((size_t)e1.w << 7) + fl * 8);
            const uint4 v2 = *(const uint4*)(fh + ((size_t)e2.w << 7) + fl * 8);
            {
                const f16x2 w0 = u2h(e1.x), w1 = u2h(e1.y), w2v = u2h(e1.z);
                const f16x2 va = u2h(v1.x), vb = u2h(v1.y), vc = u2h(v1.z), vd = u2h(v1.w);
                ac[0][0] = __builtin_elementwise_fma(va, w0, ac[0][0]);
                ac[0][1] = __builtin_elementwise_fma(vb, w0, ac[0][1]);
                ac[0][2] = __builtin_elementwise_fma(vc, w0, ac[0][2]);
                ac[0][3] = __builtin_elementwise_fma(vd, w0, ac[0][3]);
                ac[1][0] = __builtin_elementwise_fma(va, w1, ac[1][0]);
                ac[1][1] = __builtin_elementwise_fma(vb, w1, ac[1][1]);
                ac[1][2] = __builtin_elementwise_fma(vc, w1, ac[1][2]);
                ac[1][3] = __builtin_elementwise_fma(vd, w1, ac[1][3]);
                ac[2][0] = __builtin_elementwise_fma(va, w2v, ac[2][0]);
                ac[2][1] = __builtin_elementwise_fma(vb, w2v, ac[2][1]);
                ac[2][2] = __builtin_elementwise_fma(vc, w2v, ac[2][2]);
                ac[2][3] = __builtin_elementwise_fma(vd, w2v, ac[2][3]);
            }
            {
                const f16x2 w0 = u2h(e2.x), w1 = u2h(e2.y), w2v = u2h(e2.z);
                const f16x2 va = u2h(v2.x), vb = u2h(v2.y), vc = u2h(v2.z), vd = u2h(v2.w);
                ac[0][0] = __builtin_elementwise_fma(va, w0, ac[0][0]);
                ac[0][1] = __builtin_elementwise_fma(vb, w0, ac[0][1]);
                ac[0][2] = __builtin_elementwise_fma(vc, w0, ac[0][2]);
                ac[0][3] = __builtin_elementwise_fma(vd, w0, ac[0][3]);
                ac[1][0] = __builtin_elementwise_fma(va, w1, ac[1][0]);
                ac[1][1] = __builtin_elementwise_fma(vb, w1, ac[1][1]);
                ac[1][2] = __builtin_elementwise_fma(vc, w1, ac[1][2]);
                ac[1][3] = __builtin_elementwise_fma(vd, w1, ac[1][3]);
                ac[2][0] = __builtin_elementwise_fma(va, w2v, ac[2][0]);
                ac[2][1] = __builtin_elementwise_fma(vb, w2v, ac[2][1]);
                ac[2][2] = __builtin_elementwise_fma(vc, w2v, ac[2][2]);
                ac[2][3] = __builtin_elementwise_fma(vd, w2v, ac[2][3]);
            }
        }
    }
    #pragma unroll
    for (int o = 0; o < 3; ++o)
        #pragma unroll
        for (int q = 0; q < 4; ++q) {
            ac[o][q] = ac[o][q] + u2h(__shfl_xor((int)h2u(ac[o][q]), 16));
            ac[o][q] = ac[o][q] + u2h(__shfl_xor((int)h2u(ac[o][q]), 32));
        }
    if (lane < 16) {
        __fp16* row = agg + (size_t)node * 384 + fl * 8;
        *(uint4*)(row)       = make_uint4(h2u(ac[0][0]), h2u(ac[0][1]), h2u(ac[0][2]), h2u(ac[0][3]));
        *(uint4*)(row + 128) = make_uint4(h2u(ac[1][0]), h2u(ac[1][1]), h2u(ac[1][2]), h2u(ac[1][3]));
        *(uint4*)(row + 256) = make_uint4(h2u(ac[2][0]), h2u(ac[2][1]), h2u(ac[2][2]), h2u(ac[2][3]));
    }
}

// ============================================================================
// mlp_gemm: y[m,o] = relu(sum_{ki<384} agg[m,ki]*GT[o,ki] + b[o]) + BN stats.
// 64-row M-tile, K-step 64, double-buffered async global_load_lds staging.
// ============================================================================
__global__ __launch_bounds__(256)
void mlp_gemm(const __fp16* __restrict__ agg, const __fp16* __restrict__ GT,
              float* __restrict__ out, int M,
              const float* __restrict__ bias, float* __restrict__ sbuf) {
    __shared__ char smem[49152];
    const int m0 = blockIdx.x * 64;
    const int tid = threadIdx.x;
    const int wave = tid >> 6, lane = tid & 63;
    const int wm0 = wave * 16;
    const int lrow = lane & 15;
    const int kg = lane >> 4;
    const int srow = lane >> 3;
    const int schunk = lane & 7;

    auto STAGE = [&](int buf, int kc) {
        char* base = smem + buf * 24576;
        #pragma unroll
        for (int j = 0; j < 2; ++j) {
            const int rl = wave * 16 + j * 8 + srow;
            const int rg = min(m0 + rl, M - 1);
            gload16(agg + (size_t)rg * 384 + kc * 64 + ((schunk ^ (rl & 7)) << 3),
                    base + (wave * 16 + j * 8) * 128);
        }
        #pragma unroll
        for (int j = 0; j < 4; ++j) {
            const int rl = wave * 32 + j * 8 + srow;
            gload16(GT + (size_t)rl * 384 + kc * 64 + ((schunk ^ (rl & 7)) << 3),
                    base + 8192 + (wave * 32 + j * 8) * 128);
        }
    };

    f32x4 acc[8];
    #pragma unroll
    for (int b = 0; b < 8; ++b) acc[b] = (f32x4){0.f, 0.f, 0.f, 0.f};

    STAGE(0, 0);
    __syncthreads();

    for (int kc = 0; kc < 6; ++kc) {
        const int buf = kc & 1;
        if (kc < 5) STAGE(buf ^ 1, kc + 1);
        const char* Ab = smem + buf * 24576;
        const char* Bb = Ab + 8192;
        f16x8 afr[2];
        #pragma unroll
        for (int ks = 0; ks < 2; ++ks) {
            const int row = wm0 + lrow;
            afr[ks] = *(const f16x8*)(Ab + row * 128 + (((ks * 4 + kg) ^ (row & 7)) << 4));
        }
        #pragma unroll
        for (int nf = 0; nf < 8; ++nf) {
            #pragma unroll
            for (int ks = 0; ks < 2; ++ks) {
                const int row = nf * 16 + lrow;
                f16x8 bfr = *(const f16x8*)(Bb + row * 128 + (((ks * 4 + kg) ^ (row & 7)) << 4));
                acc[nf] = __builtin_amdgcn_mfma_f32_16x16x32_f16(afr[ks], bfr, acc[nf], 0, 0, 0);
            }
        }
        __syncthreads();
    }

    float s[8], s2[8], bv[8];
    #pragma unroll
    for (int nf = 0; nf < 8; ++nf) { s[nf] = 0.f; s2[nf] = 0.f; bv[nf] = bias[nf * 16 + lrow]; }
    #pragma unroll
    for (int nf = 0; nf < 8; ++nf)
        #pragma unroll
        for (int rg = 0; rg < 4; ++rg) {
            const int row = m0 + wm0 + kg * 4 + rg;
            if (row < M) {
                const float v = fmaxf(acc[nf][rg] + bv[nf], 0.f);
                out[(size_t)row * FEAT + nf * 16 + lrow] = v;
                s[nf] += v;
                s2[nf] = fmaf(v, v, s2[nf]);
            }
        }
    #pragma unroll
    for (int nf = 0; nf < 8; ++nf) {
        s[nf]  += __shfl_xor(s[nf], 16);  s[nf]  += __shfl_xor(s[nf], 32);
        s2[nf] += __shfl_xor(s2[nf], 16); s2[nf] += __shfl_xor(s2[nf], 32);
    }
    __syncthreads();
    float* red = (float*)smem;
    if (lane < 16) {
        #pragma unroll
        for (int nf = 0; nf < 8; ++nf) {
            red[wave * 256 + nf * 16 + lane]       = s[nf];
            red[wave * 256 + 128 + nf * 16 + lane] = s2[nf];
        }
    }
    __syncthreads();
    if (tid < 128) {
        const float ss = red[tid] + red[256 + tid] + red[512 + tid] + red[768 + tid];
        const float qq = red[128 + tid] + red[384 + tid] + red[640 + tid] + red[896 + tid];
        float* sb = sbuf + (blockIdx.x & (NSHARD - 1)) * 256;
        atomicAdd(sb + tid, ss);
        atomicAdd(sb + FEAT + tid, qq);
    }
}

// ---- BN normalize (sums the 16 stat shards, derives scale/shift) ----
__global__ void normalize(float* __restrict__ y, const float* __restrict__ sbuf,
                          const float* __restrict__ gamma, const float* __restrict__ beta) {
    __shared__ float sc_s[FEAT], sh_s[FEAT];
    const int t = threadIdx.x;
    if (t < FEAT) {
        float ssum = 0.f, qsum = 0.f;
        #pragma unroll
        for (int sh = 0; sh < NSHARD; ++sh) {
            ssum += sbuf[sh * 256 + t];
            qsum += sbuf[sh * 256 + 128 + t];
        }
        const float mean = ssum / (float)N_NODES;
        const float var  = qsum / (float)N_NODES - mean * mean;
        const float sc   = gamma[t] * rsqrtf(var + BN_EPS);
        sc_s[t] = sc;
        sh_s[t] = beta[t] - mean * sc;
    }
    __syncthreads();
    const int idx = blockIdx.x * blockDim.x + t;
    const int o4 = (idx & 31) * 4;
    float4 v = *(float4*)(y + (size_t)idx * 4);
    const float4 sc = *(const float4*)(sc_s + o4);
    const float4 sh = *(const float4*)(sh_s + o4);
    v.x = fmaf(v.x, sc.x, sh.x);
    v.y = fmaf(v.y, sc.y, sh.y);
    v.z = fmaf(v.z, sc.z, sh.z);
    v.w = fmaf(v.w, sc.w, sh.w);
    *(float4*)(y + (size_t)idx * 4) = v;
}

extern "C" void kernel_launch(void* const* d_in, const int* in_sizes, int n_in,
                              void* d_out, int out_size, void* d_ws, size_t ws_size,
                              hipStream_t stream) {
    const float* feature = (const float*)d_in[0];
    const float* coords  = (const float*)d_in[1];
    const int*   src     = (const int*)d_in[2];
    const int*   dst     = (const int*)d_in[3];
    const int*   order   = (const int*)d_in[4];
    const float* linear  = (const float*)d_in[5];
    const float* attW    = (const float*)d_in[6];
    const float* mlp_w   = (const float*)d_in[7];
    const float* mlp_b   = (const float*)d_in[8];
    const float* gamma   = (const float*)d_in[9];
    const float* beta    = (const float*)d_in[10];
    float* out = (float*)d_out;

    char* p = (char*)d_ws;
    __fp16* fh           = (__fp16*)p;  p += (size_t)N_NODES * FEAT * 2;   // 12.8 MB
    __fp16* agg          = (__fp16*)p;  p += (size_t)N_NODES * 384 * 2;    // 38.4 MB
    __fp16* GT           = (__fp16*)p;  p += (size_t)FEAT * 384 * 2;       // 98 KB
    float4* pk           = (float4*)p;  p += (size_t)N_NODES * 32;         // 1.6 MB
    int4*  edata         = (int4*)p;    p += (size_t)E_EDGES * 16;         // 12.8 MB
    int2*  bbuf          = (int2*)p;    p += (size_t)NBUK * BCAP * 8;      // 8.0 MB
    float* sbuf          = (float*)p;   p += NSHARD * 256 * 4;             // 4096 floats
    int*   gcur          = (int*)p;     p += 1024;                         // 256 ints
    int*   rowptr        = (int*)p;     p += 200064;
    int*   cursor        = (int*)p;     p += 200064;

    const int MB = (N_NODES + 63) / 64;          // 782
    const int AB = (E_EDGES + 2047) / 2048;      // 391

    // zeroing of sbuf|gcur happens inside g_cast (NZERO ints from sbuf)
    g_cast<<<NGC_BLKS + FEAT, 256, 0, stream>>>(feature, coords, attW,
                                                mlp_w, linear, fh, pk, GT, (int*)sbuf);

    bucketA<<<AB, 256, 0, stream>>>(src, dst, order, gcur, bbuf);
    hist2<<<NBUK, 256, 0, stream>>>(gcur, bbuf, rowptr, cursor);
    bucketB<<<NBUK * NSEG, 256, 0, stream>>>(gcur, bbuf, pk, cursor, edata);

    segagg<<<NWB_BLKS, 256, 0, stream>>>(edata, rowptr, fh, agg);

    mlp_gemm<<<MB, 256, 0, stream>>>(agg, GT, out, N_NODES, mlp_b, sbuf);
    normalize<<<(N_NODES * 32) / 256, 256, 0, stream>>>(out, sbuf, gamma, beta);
}

// Round 22
// 151.619 us; speedup vs baseline: 1.2636x; 1.0084x over previous
//
#include <hip/hip_runtime.h>

#define N_NODES 50000
#define E_EDGES 800000
#define FEAT    128
#define KORD    3
#define BN_EPS  1e-5f
#define NBUK    49          // coarse buckets (dst >> 10)
#define BCAP    20480       // bucket capacity
#define NSHARD  16          // BN-stats atomic shards
#define NSEG    128         // bucketB segments per bucket (~1 edge/thread)
#define NGC_BLKS 3125       // g_cast main blocks: 16 nodes/block (4 nodes/wave)
#define NWB_BLKS 12500      // segagg blocks (1 node/wave)
#define NZERO   4352        // ints to zero: sbuf(4096) + gcur(256)

typedef __fp16 f16x2 __attribute__((ext_vector_type(2)));
typedef __fp16 f16x8 __attribute__((ext_vector_type(8)));
typedef __attribute__((ext_vector_type(4))) float f32x4;

__device__ __forceinline__ unsigned h2u(f16x2 h) { union { f16x2 h; unsigned u; } c; c.h = h; return c.u; }
__device__ __forceinline__ f16x2 u2h(unsigned u) { union { unsigned u; f16x2 h; } c; c.u = u; return c.h; }

// async global->LDS, 16B per lane (lane lands at ldsbase + lane*16)
__device__ __forceinline__ void gload16(const void* g, void* l) {
    __builtin_amdgcn_global_load_lds(
        (const __attribute__((address_space(1))) unsigned int*)g,
        (__attribute__((address_space(3))) unsigned int*)l, 16, 0, 0);
}

// ---- per node: feature->f16, pack {coords, g=attW@f}; zero sbuf/gcur;
//      4 nodes/wave (16 lanes x 8 feats each); tail: fold GT ----
__global__ void g_cast(const float* __restrict__ feat,
                       const float* __restrict__ coords,
                       const float* __restrict__ attW,
                       const float* __restrict__ W,
                       const float* __restrict__ L,
                       __fp16* __restrict__ fh,
                       float4* __restrict__ pk,
                       __fp16* __restrict__ GT,
                       int* __restrict__ zbase) {
    __shared__ float wrow[FEAT];
    const int gtid = blockIdx.x * 256 + threadIdx.x;
    if (gtid < NZERO) zbase[gtid] = 0;       // sbuf + gcur zeroing
    if (blockIdx.x >= NGC_BLKS) {            // gprep tail blocks (128)
        const int o = blockIdx.x - NGC_BLKS;
        const int i = threadIdx.x;
        if (i < FEAT) wrow[i] = W[o * FEAT + i];
        __syncthreads();
        if (i < FEAT) {
            #pragma unroll
            for (int k = 0; k < KORD; ++k) {
                const float* lp = L + ((size_t)k * FEAT + i) * FEAT;
                float acc = 0.f;
                #pragma unroll 8
                for (int j = 0; j < FEAT; ++j) acc = fmaf(lp[j], wrow[j], acc);
                GT[(size_t)o * 384 + k * FEAT + i] = (__fp16)acc;
            }
        }
        return;
    }
    const int node = blockIdx.x * 16 + (threadIdx.x >> 4);
    const int sub  = threadIdx.x & 15;       // 8-feature slice
    const float4 fa = *(const float4*)(feat + (size_t)node * FEAT + sub * 8);
    const float4 fb = *(const float4*)(feat + (size_t)node * FEAT + sub * 8 + 4);
    uint4 ov;
    ov.x = h2u(__builtin_amdgcn_cvt_pkrtz(fa.x, fa.y));
    ov.y = h2u(__builtin_amdgcn_cvt_pkrtz(fa.z, fa.w));
    ov.z = h2u(__builtin_amdgcn_cvt_pkrtz(fb.x, fb.y));
    ov.w = h2u(__builtin_amdgcn_cvt_pkrtz(fb.z, fb.w));
    *(uint4*)(fh + (size_t)node * FEAT + sub * 8) = ov;
    float g0, g1, g2;
    {
        const float4 wa0 = *(const float4*)(attW + 0 * FEAT + sub * 8);
        const float4 wb0 = *(const float4*)(attW + 0 * FEAT + sub * 8 + 4);
        const float4 wa1 = *(const float4*)(attW + 1 * FEAT + sub * 8);
        const float4 wb1 = *(const float4*)(attW + 1 * FEAT + sub * 8 + 4);
        const float4 wa2 = *(const float4*)(attW + 2 * FEAT + sub * 8);
        const float4 wb2 = *(const float4*)(attW + 2 * FEAT + sub * 8 + 4);
        g0 = fa.x*wa0.x + fa.y*wa0.y + fa.z*wa0.z + fa.w*wa0.w
           + fb.x*wb0.x + fb.y*wb0.y + fb.z*wb0.z + fb.w*wb0.w;
        g1 = fa.x*wa1.x + fa.y*wa1.y + fa.z*wa1.z + fa.w*wa1.w
           + fb.x*wb1.x + fb.y*wb1.y + fb.z*wb1.z + fb.w*wb1.w;
        g2 = fa.x*wa2.x + fa.y*wa2.y + fa.z*wa2.z + fa.w*wa2.w
           + fb.x*wb2.x + fb.y*wb2.y + fb.z*wb2.z + fb.w*wb2.w;
    }
    #pragma unroll
    for (int off = 8; off; off >>= 1) {
        g0 += __shfl_xor(g0, off);
        g1 += __shfl_xor(g1, off);
        g2 += __shfl_xor(g2, off);
    }
    if (sub == 0) {
        const float c0 = coords[node * 3 + 0], c1 = coords[node * 3 + 1], c2 = coords[node * 3 + 2];
        pk[2 * node]     = make_float4(c0, c1, c2, g0);
        pk[2 * node + 1] = make_float4(g1, g2, 0.f, 0.f);
    }
}

// ============ CSR build ============
__global__ __launch_bounds__(256)
void bucketA(const int* __restrict__ src, const int* __restrict__ dst,
             const int* __restrict__ order,
             int* __restrict__ gcur, int2* __restrict__ bbuf) {
    __shared__ int lcnt[4][NBUK];
    __shared__ int wbase[4][NBUK];
    const int tid = threadIdx.x;
    const int wid = tid >> 6;
    if (tid < NBUK) {
        lcnt[0][tid] = 0; lcnt[1][tid] = 0; lcnt[2][tid] = 0; lcnt[3][tid] = 0;
    }
    __syncthreads();
    const int e0 = blockIdx.x * 2048;
    int b[8], r[8], so[8], dd[8];
    #pragma unroll
    for (int i = 0; i < 8; ++i) {
        const int e = e0 + i * 256 + tid;
        if (e < E_EDGES) {
            dd[i] = dst[e];
            so[i] = (order[e] << 16) | src[e];
            b[i] = dd[i] >> 10;
            r[i] = atomicAdd(&lcnt[wid][b[i]], 1);
        } else b[i] = -1;
    }
    __syncthreads();
    if (tid < NBUK) {
        const int w0 = lcnt[0][tid], w1 = lcnt[1][tid], w2 = lcnt[2][tid], w3 = lcnt[3][tid];
        const int base = atomicAdd(gcur + tid, w0 + w1 + w2 + w3);
        wbase[0][tid] = base;
        wbase[1][tid] = base + w0;
        wbase[2][tid] = base + w0 + w1;
        wbase[3][tid] = base + w0 + w1 + w2;
    }
    __syncthreads();
    #pragma unroll
    for (int i = 0; i < 8; ++i)
        if (b[i] >= 0)
            bbuf[(size_t)b[i] * BCAP + wbase[wid][b[i]] + r[i]] = make_int2(so[i], dd[i]);
}

// ---- hist2: per-bucket LDS histogram + local scan + cross-bucket prefix ----
__global__ __launch_bounds__(256)
void hist2(const int* __restrict__ gcur, const int2* __restrict__ bbuf,
           int* __restrict__ rowptr, int* __restrict__ cursor) {
    __shared__ int lhist[1024];
    __shared__ int lscan[256];
    __shared__ int boff_s;
    const int b = blockIdx.x;
    const int t = threadIdx.x;
    #pragma unroll
    for (int i = 0; i < 4; ++i) lhist[t + i * 256] = 0;
    __syncthreads();
    const int n = gcur[b];
    const int base = b << 10;
    for (int i = t; i < n; i += 256)
        atomicAdd(&lhist[bbuf[(size_t)b * BCAP + i].y - base], 1);
    __syncthreads();
    if (t < 64) {
        const int v = (t < NBUK) ? gcur[t] : 0;
        int incl = v;
        #pragma unroll
        for (int off = 1; off < 64; off <<= 1) {
            const int u = __shfl_up(incl, off);
            if (t >= off) incl += u;
        }
        if (t == b) boff_s = incl - v;
    }
    int v[4];
    #pragma unroll
    for (int i = 0; i < 4; ++i) v[i] = lhist[t * 4 + i];
    lscan[t] = v[0] + v[1] + v[2] + v[3];
    __syncthreads();
    for (int off = 1; off < 256; off <<= 1) {
        const int u = (t >= off) ? lscan[t - off] : 0;
        __syncthreads();
        lscan[t] += u;
        __syncthreads();
    }
    int excl = (t ? lscan[t - 1] : 0) + boff_s;
    #pragma unroll
    for (int i = 0; i < 4; ++i) {
        const int node = base + t * 4 + i;
        if (node < N_NODES) { rowptr[node] = excl; cursor[node] = excl; }
        excl += v[i];
    }
    if (b == 0 && t == 0) rowptr[N_NODES] = E_EDGES;
}

// ---- bucketB: CSR scatter + per-edge att/invdist (~1 edge per thread) ----
__global__ void bucketB(const int* __restrict__ gcur, const int2* __restrict__ bbuf,
                        const float4* __restrict__ pk,
                        int* __restrict__ cursor, int4* __restrict__ edata) {
    const int b = blockIdx.x / NSEG;
    const int seg = blockIdx.x % NSEG;
    const int n = gcur[b];
    const int lo = (int)((long)n * seg / NSEG), hi = (int)((long)n * (seg + 1) / NSEG);
    for (int i = lo + (int)threadIdx.x; i < hi; i += 256) {
        const int2 ent = bbuf[(size_t)b * BCAP + i];
        const int s = ent.x & 0xFFFF;
        const int d = ent.y;
        const float4 a0 = pk[2 * s], a1 = pk[2 * s + 1], c0 = pk[2 * d];
        const float dx = a0.x - c0.x, dy = a0.y - c0.y, dz = a0.z - c0.z;
        const float att  = dx * a0.w + dy * a1.x + dz * a1.y;
        const float invd = 1.f / (dx * dx + dy * dy + dz * dz + 1.f);
        const int pos = atomicAdd(cursor + d, 1);
        edata[pos] = make_int4(ent.x, __float_as_int(att), __float_as_int(invd), 0);
    }
}

// ---- segment softmax + per-order gather-aggregate (stream + fh gather) ----
__global__ void segagg(const int4* __restrict__ edata,
                       const int* __restrict__ rowptr,
                       const __fp16* __restrict__ fh,
                       __fp16* __restrict__ agg) {
    __shared__ uint4 stash[4][64];
    const int node = (blockIdx.x * blockDim.x + threadIdx.x) >> 6;
    const int lane = threadIdx.x & 63;
    const int wid  = threadIdx.x >> 6;
    if (node >= N_NODES) return;
    const int beg = rowptr[node], end = rowptr[node + 1];

    // phase 1: online (m,s) over contiguous edata; cache chunk-0 record
    int4 e0c = make_int4(0, 0xFF800000, 0, 0);   // att = -inf
    float m = -1e30f, s = 0.f;
    int nch = 0;
    for (int cb = beg; cb < end; cb += 64, ++nch) {
        const int p = cb + lane;
        float a = -1e30f;
        if (p < end) {
            const int4 e = edata[p];
            a = __int_as_float(e.y);
            if (nch == 0) e0c = e;
        }
        const float mn = fmaxf(m, a);
        s = s * __expf(m - mn) + ((p < end) ? __expf(a - mn) : 0.f);
        m = mn;
    }
    #pragma unroll
    for (int off = 32; off; off >>= 1) {
        const float mo = __shfl_xor(m, off), so_ = __shfl_xor(s, off);
        const float mn = fmaxf(m, mo);
        s = s * __expf(m - mn) + so_ * __expf(mo - mn);
        m = mn;
    }
    const float inv_s = s > 0.f ? 1.f / s : 0.f;

    // phase 2: 4-edge groups, 2 gathers in flight
    const int grp = lane >> 4;
    const int fl  = lane & 15;
    f16x2 ac[3][4];
    #pragma unroll
    for (int o = 0; o < 3; ++o)
        #pragma unroll
        for (int q = 0; q < 4; ++q) ac[o][q] = (f16x2){0, 0};

    int ch = 0;
    for (int cb = beg; cb < end; cb += 64, ++ch) {
        const int p = cb + lane;
        float wl = 0.f; int so = 0;
        if (p < end) {
            const int4 e = (ch == 0) ? e0c : edata[p];
            wl = __expf(__int_as_float(e.y) - m) * inv_s * __int_as_float(e.z);
            so = e.x;
        }
        const int k = so >> 16;
        const __fp16 wh = (__fp16)wl;
        f16x2 w2; w2.x = wh; w2.y = wh;
        const unsigned uw = h2u(w2);
        stash[wid][lane] = make_uint4(k == 0 ? uw : 0u, k == 1 ? uw : 0u,
                                      k == 2 ? uw : 0u, (unsigned)(so & 0xFFFF));
        const int ne = min(64, end - cb);
        const uint4* st = stash[wid];
        for (int t = 0; t < ne; t += 8) {
            const uint4 e1 = st[t + grp];
            const uint4 e2 = st[t + 4 + grp];
            const uint4 v1 = *(const uint4*)(fh + ((size_t)e1.w << 7) + fl * 8);
            const uint4 v2 = *(const uint4*)(fh + ((size_t)e2.w << 7) + fl * 8);
            {
                const f16x2 w0 = u2h(e1.x), w1 = u2h(e1.y), w2v = u2h(e1.z);
                const f16x2 va = u2h(v1.x), vb = u2h(v1.y), vc = u2h(v1.z), vd = u2h(v1.w);
                ac[0][0] = __builtin_elementwise_fma(va, w0, ac[0][0]);
                ac[0][1] = __builtin_elementwise_fma(vb, w0, ac[0][1]);
                ac[0][2] = __builtin_elementwise_fma(vc, w0, ac[0][2]);
                ac[0][3] = __builtin_elementwise_fma(vd, w0, ac[0][3]);
                ac[1][0] = __builtin_elementwise_fma(va, w1, ac[1][0]);
                ac[1][1] = __builtin_elementwise_fma(vb, w1, ac[1][1]);
                ac[1][2] = __builtin_elementwise_fma(vc, w1, ac[1][2]);
                ac[1][3] = __builtin_elementwise_fma(vd, w1, ac[1][3]);
                ac[2][0] = __builtin_elementwise_fma(va, w2v, ac[2][0]);
                ac[2][1] = __builtin_elementwise_fma(vb, w2v, ac[2][1]);
                ac[2][2] = __builtin_elementwise_fma(vc, w2v, ac[2][2]);
                ac[2][3] = __builtin_elementwise_fma(vd, w2v, ac[2][3]);
            }
            {
                const f16x2 w0 = u2h(e2.x), w1 = u2h(e2.y), w2v = u2h(e2.z);
                const f16x2 va = u2h(v2.x), vb = u2h(v2.y), vc = u2h(v2.z), vd = u2h(v2.w);
                ac[0][0] = __builtin_elementwise_fma(va, w0, ac[0][0]);
                ac[0][1] = __builtin_elementwise_fma(vb, w0, ac[0][1]);
                ac[0][2] = __builtin_elementwise_fma(vc, w0, ac[0][2]);
                ac[0][3] = __builtin_elementwise_fma(vd, w0, ac[0][3]);
                ac[1][0] = __builtin_elementwise_fma(va, w1, ac[1][0]);
                ac[1][1] = __builtin_elementwise_fma(vb, w1, ac[1][1]);
                ac[1][2] = __builtin_elementwise_fma(vc, w1, ac[1][2]);
                ac[1][3] = __builtin_elementwise_fma(vd, w1, ac[1][3]);
                ac[2][0] = __builtin_elementwise_fma(va, w2v, ac[2][0]);
                ac[2][1] = __builtin_elementwise_fma(vb, w2v, ac[2][1]);
                ac[2][2] = __builtin_elementwise_fma(vc, w2v, ac[2][2]);
                ac[2][3] = __builtin_elementwise_fma(vd, w2v, ac[2][3]);
            }
        }
    }
    #pragma unroll
    for (int o = 0; o < 3; ++o)
        #pragma unroll
        for (int q = 0; q < 4; ++q) {
            ac[o][q] = ac[o][q] + u2h(__shfl_xor((int)h2u(ac[o][q]), 16));
            ac[o][q] = ac[o][q] + u2h(__shfl_xor((int)h2u(ac[o][q]), 32));
        }
    if (lane < 16) {
        __fp16* row = agg + (size_t)node * 384 + fl * 8;
        *(uint4*)(row)       = make_uint4(h2u(ac[0][0]), h2u(ac[0][1]), h2u(ac[0][2]), h2u(ac[0][3]));
        *(uint4*)(row + 128) = make_uint4(h2u(ac[1][0]), h2u(ac[1][1]), h2u(ac[1][2]), h2u(ac[1][3]));
        *(uint4*)(row + 256) = make_uint4(h2u(ac[2][0]), h2u(ac[2][1]), h2u(ac[2][2]), h2u(ac[2][3]));
    }
}

// ============================================================================
// mlp_gemm: y[m,o] = relu(sum_{ki<384} agg[m,ki]*GT[o,ki] + b[o]) + BN stats.
// 64-row M-tile, K-step 64, double-buffered async global_load_lds staging.
// ============================================================================
__global__ __launch_bounds__(256)
void mlp_gemm(const __fp16* __restrict__ agg, const __fp16* __restrict__ GT,
              float* __restrict__ out, int M,
              const float* __restrict__ bias, float* __restrict__ sbuf) {
    __shared__ char smem[49152];
    const int m0 = blockIdx.x * 64;
    const int tid = threadIdx.x;
    const int wave = tid >> 6, lane = tid & 63;
    const int wm0 = wave * 16;
    const int lrow = lane & 15;
    const int kg = lane >> 4;
    const int srow = lane >> 3;
    const int schunk = lane & 7;

    auto STAGE = [&](int buf, int kc) {
        char* base = smem + buf * 24576;
        #pragma unroll
        for (int j = 0; j < 2; ++j) {
            const int rl = wave * 16 + j * 8 + srow;
            const int rg = min(m0 + rl, M - 1);
            gload16(agg + (size_t)rg * 384 + kc * 64 + ((schunk ^ (rl & 7)) << 3),
                    base + (wave * 16 + j * 8) * 128);
        }
        #pragma unroll
        for (int j = 0; j < 4; ++j) {
            const int rl = wave * 32 + j * 8 + srow;
            gload16(GT + (size_t)rl * 384 + kc * 64 + ((schunk ^ (rl & 7)) << 3),
                    base + 8192 + (wave * 32 + j * 8) * 128);
        }
    };

    f32x4 acc[8];
    #pragma unroll
    for (int b = 0; b < 8; ++b) acc[b] = (f32x4){0.f, 0.f, 0.f, 0.f};

    STAGE(0, 0);
    __syncthreads();

    for (int kc = 0; kc < 6; ++kc) {
        const int buf = kc & 1;
        if (kc < 5) STAGE(buf ^ 1, kc + 1);
        const char* Ab = smem + buf * 24576;
        const char* Bb = Ab + 8192;
        f16x8 afr[2];
        #pragma unroll
        for (int ks = 0; ks < 2; ++ks) {
            const int row = wm0 + lrow;
            afr[ks] = *(const f16x8*)(Ab + row * 128 + (((ks * 4 + kg) ^ (row & 7)) << 4));
        }
        #pragma unroll
        for (int nf = 0; nf < 8; ++nf) {
            #pragma unroll
            for (int ks = 0; ks < 2; ++ks) {
                const int row = nf * 16 + lrow;
                f16x8 bfr = *(const f16x8*)(Bb + row * 128 + (((ks * 4 + kg) ^ (row & 7)) << 4));
                acc[nf] = __builtin_amdgcn_mfma_f32_16x16x32_f16(afr[ks], bfr, acc[nf], 0, 0, 0);
            }
        }
        __syncthreads();
    }

    float s[8], s2[8], bv[8];
    #pragma unroll
    for (int nf = 0; nf < 8; ++nf) { s[nf] = 0.f; s2[nf] = 0.f; bv[nf] = bias[nf * 16 + lrow]; }
    #pragma unroll
    for (int nf = 0; nf < 8; ++nf)
        #pragma unroll
        for (int rg = 0; rg < 4; ++rg) {
            const int row = m0 + wm0 + kg * 4 + rg;
            if (row < M) {
                const float v = fmaxf(acc[nf][rg] + bv[nf], 0.f);
                out[(size_t)row * FEAT + nf * 16 + lrow] = v;
                s[nf] += v;
                s2[nf] = fmaf(v, v, s2[nf]);
            }
        }
    #pragma unroll
    for (int nf = 0; nf < 8; ++nf) {
        s[nf]  += __shfl_xor(s[nf], 16);  s[nf]  += __shfl_xor(s[nf], 32);
        s2[nf] += __shfl_xor(s2[nf], 16); s2[nf] += __shfl_xor(s2[nf], 32);
    }
    __syncthreads();
    float* red = (float*)smem;
    if (lane < 16) {
        #pragma unroll
        for (int nf = 0; nf < 8; ++nf) {
            red[wave * 256 + nf * 16 + lane]       = s[nf];
            red[wave * 256 + 128 + nf * 16 + lane] = s2[nf];
        }
    }
    __syncthreads();
    if (tid < 128) {
        const float ss = red[tid] + red[256 + tid] + red[512 + tid] + red[768 + tid];
        const float qq = red[128 + tid] + red[384 + tid] + red[640 + tid] + red[896 + tid];
        float* sb = sbuf + (blockIdx.x & (NSHARD - 1)) * 256;
        atomicAdd(sb + tid, ss);
        atomicAdd(sb + FEAT + tid, qq);
    }
}

// ---- BN normalize (sums the 16 stat shards, derives scale/shift) ----
__global__ void normalize(float* __restrict__ y, const float* __restrict__ sbuf,
                          const float* __restrict__ gamma, const float* __restrict__ beta) {
    __shared__ float sc_s[FEAT], sh_s[FEAT];
    const int t = threadIdx.x;
    if (t < FEAT) {
        float ssum = 0.f, qsum = 0.f;
        #pragma unroll
        for (int sh = 0; sh < NSHARD; ++sh) {
            ssum += sbuf[sh * 256 + t];
            qsum += sbuf[sh * 256 + 128 + t];
        }
        const float mean = ssum / (float)N_NODES;
        const float var  = qsum / (float)N_NODES - mean * mean;
        const float sc   = gamma[t] * rsqrtf(var + BN_EPS);
        sc_s[t] = sc;
        sh_s[t] = beta[t] - mean * sc;
    }
    __syncthreads();
    const int idx = blockIdx.x * blockDim.x + t;
    const int o4 = (idx & 31) * 4;
    float4 v = *(float4*)(y + (size_t)idx * 4);
    const float4 sc = *(const float4*)(sc_s + o4);
    const float4 sh = *(const float4*)(sh_s + o4);
    v.x = fmaf(v.x, sc.x, sh.x);
    v.y = fmaf(v.y, sc.y, sh.y);
    v.z = fmaf(v.z, sc.z, sh.z);
    v.w = fmaf(v.w, sc.w, sh.w);
    *(float4*)(y + (size_t)idx * 4) = v;
}

extern "C" void kernel_launch(void* const* d_in, const int* in_sizes, int n_in,
                              void* d_out, int out_size, void* d_ws, size_t ws_size,
                              hipStream_t stream) {
    const float* feature = (const float*)d_in[0];
    const float* coords  = (const float*)d_in[1];
    const int*   src     = (const int*)d_in[2];
    const int*   dst     = (const int*)d_in[3];
    const int*   order   = (const int*)d_in[4];
    const float* linear  = (const float*)d_in[5];
    const float* attW    = (const float*)d_in[6];
    const float* mlp_w   = (const float*)d_in[7];
    const float* mlp_b   = (const float*)d_in[8];
    const float* gamma   = (const float*)d_in[9];
    const float* beta    = (const float*)d_in[10];
    float* out = (float*)d_out;

    char* p = (char*)d_ws;
    __fp16* fh           = (__fp16*)p;  p += (size_t)N_NODES * FEAT * 2;   // 12.8 MB
    __fp16* agg          = (__fp16*)p;  p += (size_t)N_NODES * 384 * 2;    // 38.4 MB
    __fp16* GT           = (__fp16*)p;  p += (size_t)FEAT * 384 * 2;       // 98 KB
    float4* pk           = (float4*)p;  p += (size_t)N_NODES * 32;         // 1.6 MB
    int4*  edata         = (int4*)p;    p += (size_t)E_EDGES * 16;         // 12.8 MB
    int2*  bbuf          = (int2*)p;    p += (size_t)NBUK * BCAP * 8;      // 8.0 MB
    float* sbuf          = (float*)p;   p += NSHARD * 256 * 4;             // 4096 floats
    int*   gcur          = (int*)p;     p += 1024;                         // 256 ints
    int*   rowptr        = (int*)p;     p += 200064;
    int*   cursor        = (int*)p;     p += 200064;

    const int MB = (N_NODES + 63) / 64;          // 782
    const int AB = (E_EDGES + 2047) / 2048;      // 391

    // zeroing of sbuf|gcur happens inside g_cast (NZERO ints from sbuf)
    g_cast<<<NGC_BLKS + FEAT, 256, 0, stream>>>(feature, coords, attW,
                                                mlp_w, linear, fh, pk, GT, (int*)sbuf);

    bucketA<<<AB, 256, 0, stream>>>(src, dst, order, gcur, bbuf);
    hist2<<<NBUK, 256, 0, stream>>>(gcur, bbuf, rowptr, cursor);
    bucketB<<<NBUK * NSEG, 256, 0, stream>>>(gcur, bbuf, pk, cursor, edata);

    segagg<<<NWB_BLKS, 256, 0, stream>>>(edata, rowptr, fh, agg);

    mlp_gemm<<<MB, 256, 0, stream>>>(agg, GT, out, N_NODES, mlp_b, sbuf);
    normalize<<<(N_NODES * 32) / 256, 256, 0, stream>>>(out, sbuf, gamma, beta);
}